// Round 9
// baseline (596.428 us; speedup 1.0000x reference)
//
#include <hip/hip_runtime.h>
#include <math.h>

#define NEG_SLOPE 0.2f

typedef __attribute__((ext_vector_type(8))) short bf16x8;
typedef __attribute__((ext_vector_type(4))) float f32x4;
typedef __attribute__((ext_vector_type(4))) unsigned short u16x4;
typedef __attribute__((ext_vector_type(8))) unsigned short u16x8;

static __device__ __forceinline__ f32x4 lky4(f32x4 v) {
    f32x4 r;
    r.x = v.x >= 0.f ? v.x : NEG_SLOPE * v.x;
    r.y = v.y >= 0.f ? v.y : NEG_SLOPE * v.y;
    r.z = v.z >= 0.f ? v.z : NEG_SLOPE * v.z;
    r.w = v.w >= 0.f ? v.w : NEG_SLOPE * v.w;
    return r;
}
static __device__ __forceinline__ f32x4 exp4(f32x4 v) {
    f32x4 r;
    r.x = __expf(v.x); r.y = __expf(v.y); r.z = __expf(v.z); r.w = __expf(v.w);
    return r;
}
static __device__ __forceinline__ float bf2f(unsigned short u) {
    return __uint_as_float(((unsigned int)u) << 16);
}
static __device__ __forceinline__ unsigned short f2bf_rne(float f) {
    unsigned int u = __float_as_uint(f);
    u += 0x7fffu + ((u >> 16) & 1u);
    return (unsigned short)(u >> 16);
}

// ---------------- CSR build ----------------

__global__ void hist_kernel(const int* __restrict__ dst, int* __restrict__ counts, int E, int Nn) {
    int i = blockIdx.x * blockDim.x + threadIdx.x;
    int tot = E + Nn;
    if (i < tot) {
        int d = (i < E) ? dst[i] : (i - E);
        atomicAdd(&counts[d], 1);
    }
}

__global__ void scan1_kernel(const int* __restrict__ counts, int* __restrict__ partial,
                             int* __restrict__ blockSums, int Nn) {
    __shared__ int sh[1024];
    int b = blockIdx.x, t = threadIdx.x;
    int base = b * 1024;
    int orig[4];
    for (int r = 0; r < 4; r++) {
        int i = t + r * 256;
        int v = (base + i < Nn) ? counts[base + i] : 0;
        orig[r] = v;
        sh[i] = v;
    }
    __syncthreads();
    for (int off = 1; off < 1024; off <<= 1) {
        int vals[4];
        for (int r = 0; r < 4; r++) { int i = t + r * 256; vals[r] = (i >= off) ? sh[i - off] : 0; }
        __syncthreads();
        for (int r = 0; r < 4; r++) { int i = t + r * 256; sh[i] += vals[r]; }
        __syncthreads();
    }
    for (int r = 0; r < 4; r++) {
        int i = t + r * 256;
        if (base + i < Nn) partial[base + i] = sh[i] - orig[r];
    }
    if (t == 0) blockSums[b] = sh[1023];
}

__global__ void scan2_kernel(int* __restrict__ blockSums, int nb) {
    if (threadIdx.x == 0 && blockIdx.x == 0) {
        int s = 0;
        for (int i = 0; i < nb; i++) { int v = blockSums[i]; blockSums[i] = s; s += v; }
    }
}

__global__ void finalize_kernel(const int* __restrict__ partial, const int* __restrict__ blockOff,
                                int* __restrict__ row_ptr, int Nn, int Etot) {
    int i = blockIdx.x * blockDim.x + threadIdx.x;
    if (i < Nn) row_ptr[i] = partial[i] + blockOff[i >> 10];
    if (i == 0) row_ptr[Nn] = Etot;
}

__global__ void scatter_kernel(const int* __restrict__ srcE, const int* __restrict__ dstE,
                               const int* __restrict__ row_ptr, int* __restrict__ fill,
                               int* __restrict__ srcs, int E, int Nn) {
    int i = blockIdx.x * blockDim.x + threadIdx.x;
    int tot = E + Nn;
    if (i < tot) {
        int s, d;
        if (i < E) { s = srcE[i]; d = dstE[i]; }
        else       { s = d = i - E; }
        int pos = row_ptr[d] + atomicAdd(&fill[d], 1);
        srcs[pos] = s;
    }
}

// ---------------- degree bucketing (descending) for gather load balance ----------------

__global__ void deg_hist_kernel(const int* __restrict__ row_ptr, int* __restrict__ bcnt, int Nn) {
    int i = blockIdx.x * blockDim.x + threadIdx.x;
    if (i < Nn) {
        int d = row_ptr[i + 1] - row_ptr[i];
        int b = 255 - min(d, 255);     // descending degree
        atomicAdd(&bcnt[b], 1);
    }
}

__global__ void deg_scan_kernel(const int* __restrict__ bcnt, int* __restrict__ boff,
                                int* __restrict__ bfill) {
    __shared__ int sh[256];
    int t = threadIdx.x;
    int orig = bcnt[t];
    sh[t] = orig;
    __syncthreads();
    for (int off = 1; off < 256; off <<= 1) {
        int v = (t >= off) ? sh[t - off] : 0;
        __syncthreads();
        sh[t] += v;
        __syncthreads();
    }
    boff[t] = sh[t] - orig;   // exclusive
    bfill[t] = 0;
}

__global__ void deg_scatter_kernel(const int* __restrict__ row_ptr, const int* __restrict__ boff,
                                   int* __restrict__ bfill, int* __restrict__ node_order, int Nn) {
    int i = blockIdx.x * blockDim.x + threadIdx.x;
    if (i < Nn) {
        int d = row_ptr[i + 1] - row_ptr[i];
        int b = 255 - min(d, 255);
        int pos = boff[b] + atomicAdd(&bfill[b], 1);
        node_order[pos] = i;
    }
}

// W[k][n] fp32 -> Bt[n][k] bf16 RNE  (Bt: [256][256])
__global__ void transposeW_kernel(const float* __restrict__ W, unsigned short* __restrict__ Bt) {
    int t = blockIdx.x * 256 + threadIdx.x;   // 65536 threads
    int n = t >> 8, k = t & 255;
    Bt[(size_t)n * 256 + k] = f2bf_rne(W[k * 256 + n]);
}

// ---------------- bf16 MFMA GEMM, K=256, 2-phase double-buffered ----------------
// Gb[rows,256] (bf16 RNE) = A x Bt^T.
// F32A=1: A is fp32 (x input), staged via reg-load + RNE convert + ds_write
//         (identical numerics to a separate convert pass).
// F32A=0: A is bf16 (Ab), staged via global_load_lds.
template<int F32A>
__global__ __launch_bounds__(256) void gemm_kernel(const unsigned short* __restrict__ Ab,
                                                   const float* __restrict__ Xf,
                                                   const unsigned short* __restrict__ Bt,
                                                   unsigned short* __restrict__ Gb,
                                                   int rows) {
    __shared__ __align__(128) unsigned char smem[65536];   // 2 x (As 16KB + Bs 16KB)

    int tid = threadIdx.x;
    int lane = tid & 63, wid = tid >> 6;
    int wr = wid >> 1, wc = wid & 1;
    int bm = blockIdx.x * 128;
    int bn = blockIdx.y * 128;

    f32x4 zero4 = {0.f, 0.f, 0.f, 0.f};
    f32x4 acc[4][4];
#pragma unroll
    for (int i = 0; i < 4; i++)
#pragma unroll
        for (int j = 0; j < 4; j++) acc[i][j] = zero4;

    int sr = tid >> 3;   // 0..31
    int sc = tid & 7;    // chunk 0..7

    auto stage = [&](int kt, int buf) {
        unsigned short* As = (unsigned short*)(smem + buf * 32768);
        unsigned short* Bs = As + 8192;
#pragma unroll
        for (int q = 0; q < 4; q++) {
            int rt = q * 32 + sr;
            int gr = bm + rt; if (gr >= rows) gr = rows - 1;
            int cg = sc ^ (rt & 7);
            if (F32A) {
                const float* xp = Xf + (size_t)gr * 256 + kt + cg * 8;
                f32x4 a0 = *(const f32x4*)xp;
                f32x4 a1 = *(const f32x4*)(xp + 4);
                u16x8 v;
                v[0] = f2bf_rne(a0.x); v[1] = f2bf_rne(a0.y);
                v[2] = f2bf_rne(a0.z); v[3] = f2bf_rne(a0.w);
                v[4] = f2bf_rne(a1.x); v[5] = f2bf_rne(a1.y);
                v[6] = f2bf_rne(a1.z); v[7] = f2bf_rne(a1.w);
                *(u16x8*)(As + rt * 64 + sc * 8) = v;
            } else {
                const unsigned short* gp = Ab + (size_t)gr * 256 + kt + cg * 8;
                unsigned short* lp = As + rt * 64 + sc * 8;
                __builtin_amdgcn_global_load_lds(
                    (__attribute__((address_space(1))) void*)(uintptr_t)gp,
                    (__attribute__((address_space(3))) void*)lp, 16, 0, 0);
            }
        }
#pragma unroll
        for (int q = 0; q < 4; q++) {
            int rt = q * 32 + sr;
            int gn = bn + rt;
            int cg = sc ^ (rt & 7);
            const unsigned short* gp = Bt + (size_t)gn * 256 + kt + cg * 8;
            unsigned short* lp = Bs + rt * 64 + sc * 8;
            __builtin_amdgcn_global_load_lds(
                (__attribute__((address_space(1))) void*)(uintptr_t)gp,
                (__attribute__((address_space(3))) void*)lp, 16, 0, 0);
        }
    };

    stage(0, 0);
    __syncthreads();

    for (int kt = 0; kt < 4; kt++) {
        if (kt < 3) stage((kt + 1) * 64, (kt + 1) & 1);
        unsigned short* As = (unsigned short*)(smem + (kt & 1) * 32768);
        unsigned short* Bs = As + 8192;
#pragma unroll
        for (int ks = 0; ks < 2; ks++) {
            bf16x8 af[4], bfr[4];
#pragma unroll
            for (int f = 0; f < 4; f++) {
                int r = wr * 64 + f * 16 + (lane & 15);
                int c = (ks * 4 + (lane >> 4)) ^ (r & 7);
                af[f] = *(const bf16x8*)(As + r * 64 + c * 8);
                int rb = wc * 64 + f * 16 + (lane & 15);
                int cb = (ks * 4 + (lane >> 4)) ^ (rb & 7);
                bfr[f] = *(const bf16x8*)(Bs + rb * 64 + cb * 8);
            }
#pragma unroll
            for (int i = 0; i < 4; i++)
#pragma unroll
                for (int j = 0; j < 4; j++)
                    acc[i][j] = __builtin_amdgcn_mfma_f32_16x16x32_bf16(af[i], bfr[j], acc[i][j], 0, 0, 0);
        }
        __syncthreads();
    }

    int r0 = wr * 64 + (lane >> 4) * 4;
    int c0 = wc * 64 + (lane & 15);
#pragma unroll
    for (int i = 0; i < 4; i++) {
#pragma unroll
        for (int j = 0; j < 4; j++) {
#pragma unroll
            for (int rg = 0; rg < 4; rg++) {
                int lr = bm + r0 + i * 16 + rg;
                if (lr < rows) {
                    int col = bn + c0 + j * 16;
                    Gb[(size_t)lr * 256 + col] = f2bf_rne(acc[i][j][rg]);
                }
            }
        }
    }
}

// ---------------- attention coefficients (wave per node, bf16 G) ----------------
__global__ __launch_bounds__(256) void attn_kernel(const unsigned short* __restrict__ Gb,
                                                   const float* __restrict__ att_s,
                                                   const float* __restrict__ att_d,
                                                   float* __restrict__ a_src,
                                                   float* __restrict__ a_dst, int N) {
    int wv = threadIdx.x >> 6, lane = threadIdx.x & 63;
    int n = blockIdx.x * 4 + wv;
    if (n >= N) return;
    u16x4 g4 = *(const u16x4*)(Gb + (size_t)n * 256 + lane * 4);
    f32x4 g;
    g.x = bf2f(g4.x); g.y = bf2f(g4.y); g.z = bf2f(g4.z); g.w = bf2f(g4.w);
    f32x4 s4 = ((const f32x4*)att_s)[lane];
    f32x4 d4 = ((const f32x4*)att_d)[lane];
    f32x4 p = g * s4, q = g * d4;
    float ps = p.x + p.y + p.z + p.w;
    float pd = q.x + q.y + q.z + q.w;
#pragma unroll
    for (int off = 1; off < 16; off <<= 1) {
        ps += __shfl_xor(ps, off);
        pd += __shfl_xor(pd, off);
    }
    if ((lane & 15) == 0) {
        int head = lane >> 4;
        a_src[n * 4 + head] = ps;
        a_dst[n * 4 + head] = pd;
    }
}

// ---------------- fused softmax-weight + gather (wave per node) ----------------
// Node order comes from degree-descending node_order[] for load balance.
// Staging computes ev = exp(leaky(a_src[s]+a_dst[n])) (no max subtraction;
// softmax shift-invariant, alphas O(10)); inner loop keeps 8 rows in flight
// per half-wave (indices/weights broadcast from LDS -- no dependent chain).
// outF != null -> fp32 (+bias), no relu (final layer)
// outB != null -> relu(h)+bias as bf16 RNE (next layer's GEMM input)
__global__ __launch_bounds__(256) void gather_kernel(const unsigned short* __restrict__ Gb,
                                                     const float* __restrict__ a_src,
                                                     const float* __restrict__ a_dst,
                                                     const int* __restrict__ row_ptr,
                                                     const int* __restrict__ srcs,
                                                     const int* __restrict__ node_order,
                                                     const float* __restrict__ bias,
                                                     float* __restrict__ outF,
                                                     unsigned short* __restrict__ outB,
                                                     int N) {
    __shared__ int s_lds[4][64];
    __shared__ f32x4 w_lds[4][64];
    int wv = threadIdx.x >> 6, lane = threadIdx.x & 63;
    int idx = blockIdx.x * 4 + wv;
    if (idx >= N) return;
    int n = node_order[idx];
    int half = lane >> 5;   // which edge of a pair
    int sl = lane & 31;     // 16B slice of the 512B row
    int head = sl >> 3;

    int start = row_ptr[n], end = row_ptr[n + 1];
    const f32x4* as4p = (const f32x4*)a_src;
    f32x4 adn4 = *(const f32x4*)(a_dst + (size_t)n * 4);

    float acc[8] = {0.f, 0.f, 0.f, 0.f, 0.f, 0.f, 0.f, 0.f};
    f32x4 dsum4 = {0.f, 0.f, 0.f, 0.f};

    for (int c0 = start; c0 < end; c0 += 64) {
        int cnt = min(64, end - c0);
        if (lane < cnt) {
            int s = srcs[c0 + lane];
            f32x4 ev = exp4(lky4(as4p[s] + adn4));
            s_lds[wv][lane] = s;
            w_lds[wv][lane] = ev;
            dsum4 += ev;
        }
        // wave-private staging; compiler inserts lgkmcnt waits before reads

        int j = 0;
        // 8 rows in flight per half-wave
        for (; j + 15 < cnt; j += 16) {
            int sv_[8]; float wv_[8];
#pragma unroll
            for (int t = 0; t < 8; t++) {
                int e = j + 2 * t + half;
                sv_[t] = s_lds[wv][e];
                wv_[t] = ((const float*)&w_lds[wv][e])[head];
            }
            u16x8 gv_[8];
#pragma unroll
            for (int t = 0; t < 8; t++)
                gv_[t] = *(const u16x8*)(Gb + (size_t)sv_[t] * 256 + sl * 8);
#pragma unroll
            for (int t = 0; t < 8; t++)
#pragma unroll
                for (int k = 0; k < 8; k++)
                    acc[k] = fmaf(bf2f(gv_[t][k]), wv_[t], acc[k]);
        }
        // 4 rows in flight
        for (; j + 7 < cnt; j += 8) {
            int sv_[4]; float wv_[4];
#pragma unroll
            for (int t = 0; t < 4; t++) {
                int e = j + 2 * t + half;
                sv_[t] = s_lds[wv][e];
                wv_[t] = ((const float*)&w_lds[wv][e])[head];
            }
            u16x8 gv_[4];
#pragma unroll
            for (int t = 0; t < 4; t++)
                gv_[t] = *(const u16x8*)(Gb + (size_t)sv_[t] * 256 + sl * 8);
#pragma unroll
            for (int t = 0; t < 4; t++)
#pragma unroll
                for (int k = 0; k < 8; k++)
                    acc[k] = fmaf(bf2f(gv_[t][k]), wv_[t], acc[k]);
        }
        for (; j < cnt; j += 2) {
            int e = j + half;
            if (e < cnt) {
                int s0 = s_lds[wv][e];
                float w0 = ((const float*)&w_lds[wv][e])[head];
                u16x8 g0 = *(const u16x8*)(Gb + (size_t)s0 * 256 + sl * 8);
#pragma unroll
                for (int k = 0; k < 8; k++)
                    acc[k] = fmaf(bf2f(g0[k]), w0, acc[k]);
            }
        }
    }

    // combine halves + denominator reduce
#pragma unroll
    for (int k = 0; k < 8; k++) acc[k] += __shfl_xor(acc[k], 32);
#pragma unroll
    for (int off = 32; off; off >>= 1) {
        dsum4.x += __shfl_xor(dsum4.x, off);
        dsum4.y += __shfl_xor(dsum4.y, off);
        dsum4.z += __shfl_xor(dsum4.z, off);
        dsum4.w += __shfl_xor(dsum4.w, off);
    }
    float den = head == 0 ? dsum4.x : head == 1 ? dsum4.y : head == 2 ? dsum4.z : dsum4.w;
    float rden = 1.0f / den;

    float r[8];
    const float* bp = bias + sl * 8;
#pragma unroll
    for (int k = 0; k < 8; k++) r[k] = acc[k] * rden + bp[k];

    if (outF) {
        if (half == 0) {
            f32x4 v0 = {r[0], r[1], r[2], r[3]};
            f32x4 v1 = {r[4], r[5], r[6], r[7]};
            f32x4* op = (f32x4*)(outF + (size_t)n * 256 + sl * 8);
            op[0] = v0; op[1] = v1;
        }
    } else {
        if (half == 0) {
            u16x8 v;
#pragma unroll
            for (int k = 0; k < 8; k++) v[k] = f2bf_rne(fmaxf(r[k], 0.f));
            *(u16x8*)(outB + (size_t)n * 256 + sl * 8) = v;
        }
    }
}

// ---------------- launch ----------------

extern "C" void kernel_launch(void* const* d_in, const int* in_sizes, int n_in,
                              void* d_out, int out_size, void* d_ws, size_t ws_size,
                              hipStream_t stream) {
    const float* x   = (const float*)d_in[0];
    const int*   ei  = (const int*)d_in[1];
    const float* W1  = (const float*)d_in[2];
    const float* as1 = (const float*)d_in[3];
    const float* ad1 = (const float*)d_in[4];
    const float* b1  = (const float*)d_in[5];
    const float* W2  = (const float*)d_in[6];
    const float* as2 = (const float*)d_in[7];
    const float* ad2 = (const float*)d_in[8];
    const float* b2  = (const float*)d_in[9];

    int N = in_sizes[0] / 256;
    int E = in_sizes[1] / 2;
    int Etot = E + N;
    const int* srcE = ei;
    const int* dstE = ei + E;
    float* out = (float*)d_out;

    char* w = (char*)d_ws;
    size_t used = 0;
    auto alloc = [&](size_t bytes) -> char* {
        char* p = w + used;
        used += (bytes + 255) & ~(size_t)255;
        return p;
    };
    unsigned short* Gb = (unsigned short*)alloc((size_t)N * 256 * 2);  // GEMM output (bf16)
    unsigned short* Ab = (unsigned short*)alloc((size_t)N * 256 * 2);  // GEMM input (bf16)
    float* a_src   = (float*)alloc((size_t)N * 4 * 4);
    float* a_dst   = (float*)alloc((size_t)N * 4 * 4);
    int* counts    = (int*)alloc((size_t)N * 4);     // doubles as `fill` for scatter
    int* partial   = (int*)alloc((size_t)N * 4);
    int* row_ptr   = (int*)alloc(((size_t)N + 1) * 4);
    int* srcs      = (int*)alloc((size_t)Etot * 4);
    int* node_order= (int*)alloc((size_t)N * 4);
    int* blockSums = (int*)alloc(256 * 4);
    int* bcnt      = (int*)alloc(256 * 4);
    int* boff      = (int*)alloc(256 * 4);
    int* bfill     = (int*)alloc(256 * 4);
    unsigned short* Bt = (unsigned short*)alloc((size_t)256 * 256 * 2);

    hipMemsetAsync(counts, 0, (size_t)N * 4, stream);
    hipMemsetAsync(bcnt, 0, 256 * 4, stream);

    hist_kernel<<<(Etot + 255) / 256, 256, 0, stream>>>(dstE, counts, E, N);
    int nScanBlocks = (N + 1023) / 1024;
    scan1_kernel<<<nScanBlocks, 256, 0, stream>>>(counts, partial, blockSums, N);
    scan2_kernel<<<1, 64, 0, stream>>>(blockSums, nScanBlocks);
    finalize_kernel<<<(N + 255) / 256, 256, 0, stream>>>(partial, blockSums, row_ptr, N, Etot);
    hipMemsetAsync(counts, 0, (size_t)N * 4, stream);   // reuse as fill
    scatter_kernel<<<(Etot + 255) / 256, 256, 0, stream>>>(srcE, dstE, row_ptr, counts, srcs, E, N);

    // degree-descending node order for gather load balance
    deg_hist_kernel<<<(N + 255) / 256, 256, 0, stream>>>(row_ptr, bcnt, N);
    deg_scan_kernel<<<1, 256, 0, stream>>>(bcnt, boff, bfill);
    deg_scatter_kernel<<<(N + 255) / 256, 256, 0, stream>>>(row_ptr, boff, bfill, node_order, N);

    int nodeBlocks = (N + 3) / 4;
    dim3 gg((N + 127) / 128, 2);

    // layer 1 (A staged from fp32 x inside the GEMM)
    transposeW_kernel<<<256, 256, 0, stream>>>(W1, Bt);
    gemm_kernel<1><<<gg, 256, 0, stream>>>(nullptr, x, Bt, Gb, N);
    attn_kernel<<<nodeBlocks, 256, 0, stream>>>(Gb, as1, ad1, a_src, a_dst, N);
    gather_kernel<<<nodeBlocks, 256, 0, stream>>>(Gb, a_src, a_dst, row_ptr, srcs, node_order,
                                                  b1, nullptr, Ab, N);   // relu+bf16 -> layer-2 A

    // layer 2
    transposeW_kernel<<<256, 256, 0, stream>>>(W2, Bt);
    gemm_kernel<0><<<gg, 256, 0, stream>>>(Ab, nullptr, Bt, Gb, N);
    attn_kernel<<<nodeBlocks, 256, 0, stream>>>(Gb, as2, ad2, a_src, a_dst, N);
    gather_kernel<<<nodeBlocks, 256, 0, stream>>>(Gb, a_src, a_dst, row_ptr, srcs, node_order,
                                                  b2, out, nullptr, N);  // fp32 final
}

// Round 10
// 320.632 us; speedup vs baseline: 1.8602x; 1.8602x over previous
//
#include <hip/hip_runtime.h>
#include <math.h>

#define NEG_SLOPE 0.2f

typedef __attribute__((ext_vector_type(8))) short bf16x8;
typedef __attribute__((ext_vector_type(4))) float f32x4;
typedef __attribute__((ext_vector_type(4))) unsigned short u16x4;
typedef __attribute__((ext_vector_type(8))) unsigned short u16x8;

static __device__ __forceinline__ f32x4 lky4(f32x4 v) {
    f32x4 r;
    r.x = v.x >= 0.f ? v.x : NEG_SLOPE * v.x;
    r.y = v.y >= 0.f ? v.y : NEG_SLOPE * v.y;
    r.z = v.z >= 0.f ? v.z : NEG_SLOPE * v.z;
    r.w = v.w >= 0.f ? v.w : NEG_SLOPE * v.w;
    return r;
}
static __device__ __forceinline__ f32x4 exp4(f32x4 v) {
    f32x4 r;
    r.x = __expf(v.x); r.y = __expf(v.y); r.z = __expf(v.z); r.w = __expf(v.w);
    return r;
}
static __device__ __forceinline__ float bf2f(unsigned short u) {
    return __uint_as_float(((unsigned int)u) << 16);
}
static __device__ __forceinline__ unsigned short f2bf_rne(float f) {
    unsigned int u = __float_as_uint(f);
    u += 0x7fffu + ((u >> 16) & 1u);
    return (unsigned short)(u >> 16);
}

// ---------------- CSR build ----------------

__global__ void hist_kernel(const int* __restrict__ dst, int* __restrict__ counts, int E, int Nn) {
    int i = blockIdx.x * blockDim.x + threadIdx.x;
    int tot = E + Nn;
    if (i < tot) {
        int d = (i < E) ? dst[i] : (i - E);
        atomicAdd(&counts[d], 1);
    }
}

__global__ void scan1_kernel(const int* __restrict__ counts, int* __restrict__ partial,
                             int* __restrict__ blockSums, int Nn) {
    __shared__ int sh[1024];
    int b = blockIdx.x, t = threadIdx.x;
    int base = b * 1024;
    int orig[4];
    for (int r = 0; r < 4; r++) {
        int i = t + r * 256;
        int v = (base + i < Nn) ? counts[base + i] : 0;
        orig[r] = v;
        sh[i] = v;
    }
    __syncthreads();
    for (int off = 1; off < 1024; off <<= 1) {
        int vals[4];
        for (int r = 0; r < 4; r++) { int i = t + r * 256; vals[r] = (i >= off) ? sh[i - off] : 0; }
        __syncthreads();
        for (int r = 0; r < 4; r++) { int i = t + r * 256; sh[i] += vals[r]; }
        __syncthreads();
    }
    for (int r = 0; r < 4; r++) {
        int i = t + r * 256;
        if (base + i < Nn) partial[base + i] = sh[i] - orig[r];
    }
    if (t == 0) blockSums[b] = sh[1023];
}

__global__ void scan2_kernel(int* __restrict__ blockSums, int nb) {
    if (threadIdx.x == 0 && blockIdx.x == 0) {
        int s = 0;
        for (int i = 0; i < nb; i++) { int v = blockSums[i]; blockSums[i] = s; s += v; }
    }
}

__global__ void finalize_kernel(const int* __restrict__ partial, const int* __restrict__ blockOff,
                                int* __restrict__ row_ptr, int Nn, int Etot) {
    int i = blockIdx.x * blockDim.x + threadIdx.x;
    if (i < Nn) row_ptr[i] = partial[i] + blockOff[i >> 10];
    if (i == 0) row_ptr[Nn] = Etot;
}

__global__ void scatter_kernel(const int* __restrict__ srcE, const int* __restrict__ dstE,
                               const int* __restrict__ row_ptr, int* __restrict__ fill,
                               int* __restrict__ srcs, int E, int Nn) {
    int i = blockIdx.x * blockDim.x + threadIdx.x;
    int tot = E + Nn;
    if (i < tot) {
        int s, d;
        if (i < E) { s = srcE[i]; d = dstE[i]; }
        else       { s = d = i - E; }
        int pos = row_ptr[d] + atomicAdd(&fill[d], 1);
        srcs[pos] = s;
    }
}

// W[k][n] fp32 -> Bt[n][k] bf16 RNE  (Bt: [256][256])
__global__ void transposeW_kernel(const float* __restrict__ W, unsigned short* __restrict__ Bt) {
    int t = blockIdx.x * 256 + threadIdx.x;   // 65536 threads
    int n = t >> 8, k = t & 255;
    Bt[(size_t)n * 256 + k] = f2bf_rne(W[k * 256 + n]);
}

// ---------------- bf16 MFMA GEMM, K=256, 2-phase double-buffered ----------------
// Gb[rows,256] (bf16 RNE) = A x Bt^T.
// F32A=1: A is fp32 (x input), staged via reg-load + RNE convert + ds_write.
// F32A=0: A is bf16 (Ab), staged via global_load_lds.
template<int F32A>
__global__ __launch_bounds__(256) void gemm_kernel(const unsigned short* __restrict__ Ab,
                                                   const float* __restrict__ Xf,
                                                   const unsigned short* __restrict__ Bt,
                                                   unsigned short* __restrict__ Gb,
                                                   int rows) {
    __shared__ __align__(128) unsigned char smem[65536];   // 2 x (As 16KB + Bs 16KB)

    int tid = threadIdx.x;
    int lane = tid & 63, wid = tid >> 6;
    int wr = wid >> 1, wc = wid & 1;
    int bm = blockIdx.x * 128;
    int bn = blockIdx.y * 128;

    f32x4 zero4 = {0.f, 0.f, 0.f, 0.f};
    f32x4 acc[4][4];
#pragma unroll
    for (int i = 0; i < 4; i++)
#pragma unroll
        for (int j = 0; j < 4; j++) acc[i][j] = zero4;

    int sr = tid >> 3;   // 0..31
    int sc = tid & 7;    // chunk 0..7

    auto stage = [&](int kt, int buf) {
        unsigned short* As = (unsigned short*)(smem + buf * 32768);
        unsigned short* Bs = As + 8192;
#pragma unroll
        for (int q = 0; q < 4; q++) {
            int rt = q * 32 + sr;
            int gr = bm + rt; if (gr >= rows) gr = rows - 1;
            int cg = sc ^ (rt & 7);
            if (F32A) {
                const float* xp = Xf + (size_t)gr * 256 + kt + cg * 8;
                f32x4 a0 = *(const f32x4*)xp;
                f32x4 a1 = *(const f32x4*)(xp + 4);
                u16x8 v;
                v[0] = f2bf_rne(a0.x); v[1] = f2bf_rne(a0.y);
                v[2] = f2bf_rne(a0.z); v[3] = f2bf_rne(a0.w);
                v[4] = f2bf_rne(a1.x); v[5] = f2bf_rne(a1.y);
                v[6] = f2bf_rne(a1.z); v[7] = f2bf_rne(a1.w);
                *(u16x8*)(As + rt * 64 + sc * 8) = v;
            } else {
                const unsigned short* gp = Ab + (size_t)gr * 256 + kt + cg * 8;
                unsigned short* lp = As + rt * 64 + sc * 8;
                __builtin_amdgcn_global_load_lds(
                    (__attribute__((address_space(1))) void*)(uintptr_t)gp,
                    (__attribute__((address_space(3))) void*)lp, 16, 0, 0);
            }
        }
#pragma unroll
        for (int q = 0; q < 4; q++) {
            int rt = q * 32 + sr;
            int gn = bn + rt;
            int cg = sc ^ (rt & 7);
            const unsigned short* gp = Bt + (size_t)gn * 256 + kt + cg * 8;
            unsigned short* lp = Bs + rt * 64 + sc * 8;
            __builtin_amdgcn_global_load_lds(
                (__attribute__((address_space(1))) void*)(uintptr_t)gp,
                (__attribute__((address_space(3))) void*)lp, 16, 0, 0);
        }
    };

    stage(0, 0);
    __syncthreads();

    for (int kt = 0; kt < 4; kt++) {
        if (kt < 3) stage((kt + 1) * 64, (kt + 1) & 1);
        unsigned short* As = (unsigned short*)(smem + (kt & 1) * 32768);
        unsigned short* Bs = As + 8192;
#pragma unroll
        for (int ks = 0; ks < 2; ks++) {
            bf16x8 af[4], bfr[4];
#pragma unroll
            for (int f = 0; f < 4; f++) {
                int r = wr * 64 + f * 16 + (lane & 15);
                int c = (ks * 4 + (lane >> 4)) ^ (r & 7);
                af[f] = *(const bf16x8*)(As + r * 64 + c * 8);
                int rb = wc * 64 + f * 16 + (lane & 15);
                int cb = (ks * 4 + (lane >> 4)) ^ (rb & 7);
                bfr[f] = *(const bf16x8*)(Bs + rb * 64 + cb * 8);
            }
#pragma unroll
            for (int i = 0; i < 4; i++)
#pragma unroll
                for (int j = 0; j < 4; j++)
                    acc[i][j] = __builtin_amdgcn_mfma_f32_16x16x32_bf16(af[i], bfr[j], acc[i][j], 0, 0, 0);
        }
        __syncthreads();
    }

    int r0 = wr * 64 + (lane >> 4) * 4;
    int c0 = wc * 64 + (lane & 15);
#pragma unroll
    for (int i = 0; i < 4; i++) {
#pragma unroll
        for (int j = 0; j < 4; j++) {
#pragma unroll
            for (int rg = 0; rg < 4; rg++) {
                int lr = bm + r0 + i * 16 + rg;
                if (lr < rows) {
                    int col = bn + c0 + j * 16;
                    Gb[(size_t)lr * 256 + col] = f2bf_rne(acc[i][j][rg]);
                }
            }
        }
    }
}

// ---------------- attention coefficients (wave per node, bf16 G) ----------------
__global__ __launch_bounds__(256) void attn_kernel(const unsigned short* __restrict__ Gb,
                                                   const float* __restrict__ att_s,
                                                   const float* __restrict__ att_d,
                                                   float* __restrict__ a_src,
                                                   float* __restrict__ a_dst, int N) {
    int wv = threadIdx.x >> 6, lane = threadIdx.x & 63;
    int n = blockIdx.x * 4 + wv;
    if (n >= N) return;
    u16x4 g4 = *(const u16x4*)(Gb + (size_t)n * 256 + lane * 4);
    f32x4 g;
    g.x = bf2f(g4.x); g.y = bf2f(g4.y); g.z = bf2f(g4.z); g.w = bf2f(g4.w);
    f32x4 s4 = ((const f32x4*)att_s)[lane];
    f32x4 d4 = ((const f32x4*)att_d)[lane];
    f32x4 p = g * s4, q = g * d4;
    float ps = p.x + p.y + p.z + p.w;
    float pd = q.x + q.y + q.z + q.w;
#pragma unroll
    for (int off = 1; off < 16; off <<= 1) {
        ps += __shfl_xor(ps, off);
        pd += __shfl_xor(pd, off);
    }
    if ((lane & 15) == 0) {
        int head = lane >> 4;
        a_src[n * 4 + head] = ps;
        a_dst[n * 4 + head] = pd;
    }
}

// ---------------- fused softmax-weight + gather (wave per node) ----------------
// Staging computes ev = exp(leaky(a_src[s]+a_dst[n])) (no max subtraction;
// softmax shift-invariant, alphas O(10)); inner loop keeps 8 rows in flight
// per half-wave (indices/weights broadcast from LDS -- no dependent chain).
// outF != null -> fp32 (+bias), no relu (final layer)
// outB != null -> relu(h)+bias as bf16 RNE (next layer's GEMM input)
__global__ __launch_bounds__(256) void gather_kernel(const unsigned short* __restrict__ Gb,
                                                     const float* __restrict__ a_src,
                                                     const float* __restrict__ a_dst,
                                                     const int* __restrict__ row_ptr,
                                                     const int* __restrict__ srcs,
                                                     const float* __restrict__ bias,
                                                     float* __restrict__ outF,
                                                     unsigned short* __restrict__ outB,
                                                     int N) {
    __shared__ int s_lds[4][64];
    __shared__ f32x4 w_lds[4][64];
    int wv = threadIdx.x >> 6, lane = threadIdx.x & 63;
    int n = blockIdx.x * 4 + wv;
    if (n >= N) return;
    int half = lane >> 5;   // which edge of a pair
    int sl = lane & 31;     // 16B slice of the 512B row
    int head = sl >> 3;

    int start = row_ptr[n], end = row_ptr[n + 1];
    const f32x4* as4p = (const f32x4*)a_src;
    f32x4 adn4 = *(const f32x4*)(a_dst + (size_t)n * 4);

    float acc[8] = {0.f, 0.f, 0.f, 0.f, 0.f, 0.f, 0.f, 0.f};
    f32x4 dsum4 = {0.f, 0.f, 0.f, 0.f};

    for (int c0 = start; c0 < end; c0 += 64) {
        int cnt = min(64, end - c0);
        if (lane < cnt) {
            int s = srcs[c0 + lane];
            f32x4 ev = exp4(lky4(as4p[s] + adn4));
            s_lds[wv][lane] = s;
            w_lds[wv][lane] = ev;
            dsum4 += ev;
        }
        // wave-private staging; compiler inserts lgkmcnt waits before reads

        int j = 0;
        // 8 rows in flight per half-wave
        for (; j + 15 < cnt; j += 16) {
            int sv_[8]; float wv_[8];
#pragma unroll
            for (int t = 0; t < 8; t++) {
                int e = j + 2 * t + half;
                sv_[t] = s_lds[wv][e];
                wv_[t] = ((const float*)&w_lds[wv][e])[head];
            }
            u16x8 gv_[8];
#pragma unroll
            for (int t = 0; t < 8; t++)
                gv_[t] = *(const u16x8*)(Gb + (size_t)sv_[t] * 256 + sl * 8);
#pragma unroll
            for (int t = 0; t < 8; t++)
#pragma unroll
                for (int k = 0; k < 8; k++)
                    acc[k] = fmaf(bf2f(gv_[t][k]), wv_[t], acc[k]);
        }
        // 4 rows in flight
        for (; j + 7 < cnt; j += 8) {
            int sv_[4]; float wv_[4];
#pragma unroll
            for (int t = 0; t < 4; t++) {
                int e = j + 2 * t + half;
                sv_[t] = s_lds[wv][e];
                wv_[t] = ((const float*)&w_lds[wv][e])[head];
            }
            u16x8 gv_[4];
#pragma unroll
            for (int t = 0; t < 4; t++)
                gv_[t] = *(const u16x8*)(Gb + (size_t)sv_[t] * 256 + sl * 8);
#pragma unroll
            for (int t = 0; t < 4; t++)
#pragma unroll
                for (int k = 0; k < 8; k++)
                    acc[k] = fmaf(bf2f(gv_[t][k]), wv_[t], acc[k]);
        }
        for (; j < cnt; j += 2) {
            int e = j + half;
            if (e < cnt) {
                int s0 = s_lds[wv][e];
                float w0 = ((const float*)&w_lds[wv][e])[head];
                u16x8 g0 = *(const u16x8*)(Gb + (size_t)s0 * 256 + sl * 8);
#pragma unroll
                for (int k = 0; k < 8; k++)
                    acc[k] = fmaf(bf2f(g0[k]), w0, acc[k]);
            }
        }
    }

    // combine halves + denominator reduce
#pragma unroll
    for (int k = 0; k < 8; k++) acc[k] += __shfl_xor(acc[k], 32);
#pragma unroll
    for (int off = 32; off; off >>= 1) {
        dsum4.x += __shfl_xor(dsum4.x, off);
        dsum4.y += __shfl_xor(dsum4.y, off);
        dsum4.z += __shfl_xor(dsum4.z, off);
        dsum4.w += __shfl_xor(dsum4.w, off);
    }
    float den = head == 0 ? dsum4.x : head == 1 ? dsum4.y : head == 2 ? dsum4.z : dsum4.w;
    float rden = 1.0f / den;

    float r[8];
    const float* bp = bias + sl * 8;
#pragma unroll
    for (int k = 0; k < 8; k++) r[k] = acc[k] * rden + bp[k];

    if (outF) {
        if (half == 0) {
            f32x4 v0 = {r[0], r[1], r[2], r[3]};
            f32x4 v1 = {r[4], r[5], r[6], r[7]};
            f32x4* op = (f32x4*)(outF + (size_t)n * 256 + sl * 8);
            op[0] = v0; op[1] = v1;
        }
    } else {
        if (half == 0) {
            u16x8 v;
#pragma unroll
            for (int k = 0; k < 8; k++) v[k] = f2bf_rne(fmaxf(r[k], 0.f));
            *(u16x8*)(outB + (size_t)n * 256 + sl * 8) = v;
        }
    }
}

// ---------------- launch ----------------

extern "C" void kernel_launch(void* const* d_in, const int* in_sizes, int n_in,
                              void* d_out, int out_size, void* d_ws, size_t ws_size,
                              hipStream_t stream) {
    const float* x   = (const float*)d_in[0];
    const int*   ei  = (const int*)d_in[1];
    const float* W1  = (const float*)d_in[2];
    const float* as1 = (const float*)d_in[3];
    const float* ad1 = (const float*)d_in[4];
    const float* b1  = (const float*)d_in[5];
    const float* W2  = (const float*)d_in[6];
    const float* as2 = (const float*)d_in[7];
    const float* ad2 = (const float*)d_in[8];
    const float* b2  = (const float*)d_in[9];

    int N = in_sizes[0] / 256;
    int E = in_sizes[1] / 2;
    int Etot = E + N;
    const int* srcE = ei;
    const int* dstE = ei + E;
    float* out = (float*)d_out;

    char* w = (char*)d_ws;
    size_t used = 0;
    auto alloc = [&](size_t bytes) -> char* {
        char* p = w + used;
        used += (bytes + 255) & ~(size_t)255;
        return p;
    };
    unsigned short* Gb = (unsigned short*)alloc((size_t)N * 256 * 2);  // GEMM output (bf16)
    unsigned short* Ab = (unsigned short*)alloc((size_t)N * 256 * 2);  // GEMM input (bf16)
    float* a_src   = (float*)alloc((size_t)N * 4 * 4);
    float* a_dst   = (float*)alloc((size_t)N * 4 * 4);
    int* counts    = (int*)alloc((size_t)N * 4);     // doubles as `fill` for scatter
    int* partial   = (int*)alloc((size_t)N * 4);
    int* row_ptr   = (int*)alloc(((size_t)N + 1) * 4);
    int* srcs      = (int*)alloc((size_t)Etot * 4);
    int* blockSums = (int*)alloc(256 * 4);
    unsigned short* Bt = (unsigned short*)alloc((size_t)256 * 256 * 2);

    hipMemsetAsync(counts, 0, (size_t)N * 4, stream);

    hist_kernel<<<(Etot + 255) / 256, 256, 0, stream>>>(dstE, counts, E, N);
    int nScanBlocks = (N + 1023) / 1024;
    scan1_kernel<<<nScanBlocks, 256, 0, stream>>>(counts, partial, blockSums, N);
    scan2_kernel<<<1, 64, 0, stream>>>(blockSums, nScanBlocks);
    finalize_kernel<<<(N + 255) / 256, 256, 0, stream>>>(partial, blockSums, row_ptr, N, Etot);
    hipMemsetAsync(counts, 0, (size_t)N * 4, stream);   // reuse as fill
    scatter_kernel<<<(Etot + 255) / 256, 256, 0, stream>>>(srcE, dstE, row_ptr, counts, srcs, E, N);

    int nodeBlocks = (N + 3) / 4;
    dim3 gg((N + 127) / 128, 2);

    // layer 1 (A staged from fp32 x inside the GEMM)
    transposeW_kernel<<<256, 256, 0, stream>>>(W1, Bt);
    gemm_kernel<1><<<gg, 256, 0, stream>>>(nullptr, x, Bt, Gb, N);
    attn_kernel<<<nodeBlocks, 256, 0, stream>>>(Gb, as1, ad1, a_src, a_dst, N);
    gather_kernel<<<nodeBlocks, 256, 0, stream>>>(Gb, a_src, a_dst, row_ptr, srcs,
                                                  b1, nullptr, Ab, N);   // relu+bf16 -> layer-2 A

    // layer 2
    transposeW_kernel<<<256, 256, 0, stream>>>(W2, Bt);
    gemm_kernel<0><<<gg, 256, 0, stream>>>(Ab, nullptr, Bt, Gb, N);
    attn_kernel<<<nodeBlocks, 256, 0, stream>>>(Gb, as2, ad2, a_src, a_dst, N);
    gather_kernel<<<nodeBlocks, 256, 0, stream>>>(Gb, a_src, a_dst, row_ptr, srcs,
                                                  b2, out, nullptr, N);  // fp32 final
}

// Round 11
// 301.920 us; speedup vs baseline: 1.9754x; 1.0620x over previous
//
#include <hip/hip_runtime.h>
#include <math.h>

#define NEG_SLOPE 0.2f

typedef __attribute__((ext_vector_type(8))) short bf16x8;
typedef __attribute__((ext_vector_type(4))) float f32x4;
typedef __attribute__((ext_vector_type(4))) unsigned short u16x4;
typedef __attribute__((ext_vector_type(8))) unsigned short u16x8;

static __device__ __forceinline__ f32x4 lky4(f32x4 v) {
    f32x4 r;
    r.x = v.x >= 0.f ? v.x : NEG_SLOPE * v.x;
    r.y = v.y >= 0.f ? v.y : NEG_SLOPE * v.y;
    r.z = v.z >= 0.f ? v.z : NEG_SLOPE * v.z;
    r.w = v.w >= 0.f ? v.w : NEG_SLOPE * v.w;
    return r;
}
static __device__ __forceinline__ f32x4 exp4(f32x4 v) {
    f32x4 r;
    r.x = __expf(v.x); r.y = __expf(v.y); r.z = __expf(v.z); r.w = __expf(v.w);
    return r;
}
static __device__ __forceinline__ float bf2f(unsigned short u) {
    return __uint_as_float(((unsigned int)u) << 16);
}
static __device__ __forceinline__ unsigned short f2bf_rne(float f) {
    unsigned int u = __float_as_uint(f);
    u += 0x7fffu + ((u >> 16) & 1u);
    return (unsigned short)(u >> 16);
}

// ---------------- CSR build ----------------

__global__ void hist_kernel(const int* __restrict__ dst, int* __restrict__ counts, int E, int Nn) {
    int i = blockIdx.x * blockDim.x + threadIdx.x;
    int tot = E + Nn;
    if (i < tot) {
        int d = (i < E) ? dst[i] : (i - E);
        atomicAdd(&counts[d], 1);
    }
}

__global__ void scan1_kernel(const int* __restrict__ counts, int* __restrict__ partial,
                             int* __restrict__ blockSums, int Nn) {
    __shared__ int sh[1024];
    int b = blockIdx.x, t = threadIdx.x;
    int base = b * 1024;
    int orig[4];
    for (int r = 0; r < 4; r++) {
        int i = t + r * 256;
        int v = (base + i < Nn) ? counts[base + i] : 0;
        orig[r] = v;
        sh[i] = v;
    }
    __syncthreads();
    for (int off = 1; off < 1024; off <<= 1) {
        int vals[4];
        for (int r = 0; r < 4; r++) { int i = t + r * 256; vals[r] = (i >= off) ? sh[i - off] : 0; }
        __syncthreads();
        for (int r = 0; r < 4; r++) { int i = t + r * 256; sh[i] += vals[r]; }
        __syncthreads();
    }
    for (int r = 0; r < 4; r++) {
        int i = t + r * 256;
        if (base + i < Nn) partial[base + i] = sh[i] - orig[r];
    }
    if (t == 0) blockSums[b] = sh[1023];
}

__global__ void scan2_kernel(int* __restrict__ blockSums, int nb) {
    if (threadIdx.x == 0 && blockIdx.x == 0) {
        int s = 0;
        for (int i = 0; i < nb; i++) { int v = blockSums[i]; blockSums[i] = s; s += v; }
    }
}

__global__ void finalize_kernel(const int* __restrict__ partial, const int* __restrict__ blockOff,
                                int* __restrict__ row_ptr, int Nn, int Etot) {
    int i = blockIdx.x * blockDim.x + threadIdx.x;
    if (i < Nn) row_ptr[i] = partial[i] + blockOff[i >> 10];
    if (i == 0) row_ptr[Nn] = Etot;
}

__global__ void scatter_kernel(const int* __restrict__ srcE, const int* __restrict__ dstE,
                               const int* __restrict__ row_ptr, int* __restrict__ fill,
                               int* __restrict__ srcs, int E, int Nn) {
    int i = blockIdx.x * blockDim.x + threadIdx.x;
    int tot = E + Nn;
    if (i < tot) {
        int s, d;
        if (i < E) { s = srcE[i]; d = dstE[i]; }
        else       { s = d = i - E; }
        int pos = row_ptr[d] + atomicAdd(&fill[d], 1);
        srcs[pos] = s;
    }
}

// ---------------- fp32 -> bf16 RNE ----------------
__global__ void convertA_kernel(const float* __restrict__ X, unsigned short* __restrict__ Ab,
                                int rows) {
    int t = blockIdx.x * 256 + threadIdx.x;
    if (t >= rows * 64) return;
    int r = t >> 6, c4 = t & 63;
    f32x4 v = *((const f32x4*)(X + ((size_t)r << 8)) + c4);
    u16x4 o;
    o.x = f2bf_rne(v.x); o.y = f2bf_rne(v.y);
    o.z = f2bf_rne(v.z); o.w = f2bf_rne(v.w);
    *(u16x4*)(Ab + (size_t)r * 256 + c4 * 4) = o;
}

// W[k][n] fp32 -> Bt[n][k] bf16 RNE  (Bt: [256][256])
__global__ void transposeW_kernel(const float* __restrict__ W, unsigned short* __restrict__ Bt) {
    int t = blockIdx.x * 256 + threadIdx.x;   // 65536 threads
    int n = t >> 8, k = t & 255;
    Bt[(size_t)n * 256 + k] = f2bf_rne(W[k * 256 + n]);
}

// ---------------- bf16 MFMA GEMM, K=256, 2-phase double-buffered ----------------
// Gb[rows,256] (bf16 RNE) = Ab x Bt^T.
__global__ __launch_bounds__(256) void gemm_kernel(const unsigned short* __restrict__ Ab,
                                                   const unsigned short* __restrict__ Bt,
                                                   unsigned short* __restrict__ Gb,
                                                   int rows) {
    __shared__ __align__(128) unsigned char smem[65536];   // 2 x (As 16KB + Bs 16KB)

    int tid = threadIdx.x;
    int lane = tid & 63, wid = tid >> 6;
    int wr = wid >> 1, wc = wid & 1;
    int bm = blockIdx.x * 128;
    int bn = blockIdx.y * 128;

    f32x4 zero4 = {0.f, 0.f, 0.f, 0.f};
    f32x4 acc[4][4];
#pragma unroll
    for (int i = 0; i < 4; i++)
#pragma unroll
        for (int j = 0; j < 4; j++) acc[i][j] = zero4;

    int sr = tid >> 3;   // 0..31
    int sc = tid & 7;    // chunk 0..7

    auto stage = [&](int kt, int buf) {
        unsigned short* As = (unsigned short*)(smem + buf * 32768);
        unsigned short* Bs = As + 8192;
#pragma unroll
        for (int q = 0; q < 4; q++) {
            int rt = q * 32 + sr;
            int gr = bm + rt; if (gr >= rows) gr = rows - 1;
            int cg = sc ^ (rt & 7);
            const unsigned short* gp = Ab + (size_t)gr * 256 + kt + cg * 8;
            unsigned short* lp = As + rt * 64 + sc * 8;
            __builtin_amdgcn_global_load_lds(
                (__attribute__((address_space(1))) void*)(uintptr_t)gp,
                (__attribute__((address_space(3))) void*)lp, 16, 0, 0);
        }
#pragma unroll
        for (int q = 0; q < 4; q++) {
            int rt = q * 32 + sr;
            int gn = bn + rt;
            int cg = sc ^ (rt & 7);
            const unsigned short* gp = Bt + (size_t)gn * 256 + kt + cg * 8;
            unsigned short* lp = Bs + rt * 64 + sc * 8;
            __builtin_amdgcn_global_load_lds(
                (__attribute__((address_space(1))) void*)(uintptr_t)gp,
                (__attribute__((address_space(3))) void*)lp, 16, 0, 0);
        }
    };

    stage(0, 0);
    __syncthreads();

    for (int kt = 0; kt < 4; kt++) {
        if (kt < 3) stage((kt + 1) * 64, (kt + 1) & 1);
        unsigned short* As = (unsigned short*)(smem + (kt & 1) * 32768);
        unsigned short* Bs = As + 8192;
#pragma unroll
        for (int ks = 0; ks < 2; ks++) {
            bf16x8 af[4], bfr[4];
#pragma unroll
            for (int f = 0; f < 4; f++) {
                int r = wr * 64 + f * 16 + (lane & 15);
                int c = (ks * 4 + (lane >> 4)) ^ (r & 7);
                af[f] = *(const bf16x8*)(As + r * 64 + c * 8);
                int rb = wc * 64 + f * 16 + (lane & 15);
                int cb = (ks * 4 + (lane >> 4)) ^ (rb & 7);
                bfr[f] = *(const bf16x8*)(Bs + rb * 64 + cb * 8);
            }
#pragma unroll
            for (int i = 0; i < 4; i++)
#pragma unroll
                for (int j = 0; j < 4; j++)
                    acc[i][j] = __builtin_amdgcn_mfma_f32_16x16x32_bf16(af[i], bfr[j], acc[i][j], 0, 0, 0);
        }
        __syncthreads();
    }

    int r0 = wr * 64 + (lane >> 4) * 4;
    int c0 = wc * 64 + (lane & 15);
#pragma unroll
    for (int i = 0; i < 4; i++) {
#pragma unroll
        for (int j = 0; j < 4; j++) {
#pragma unroll
            for (int rg = 0; rg < 4; rg++) {
                int lr = bm + r0 + i * 16 + rg;
                if (lr < rows) {
                    int col = bn + c0 + j * 16;
                    Gb[(size_t)lr * 256 + col] = f2bf_rne(acc[i][j][rg]);
                }
            }
        }
    }
}

// ---------------- attention coefficients (wave per node, bf16 G) ----------------
__global__ __launch_bounds__(256) void attn_kernel(const unsigned short* __restrict__ Gb,
                                                   const float* __restrict__ att_s,
                                                   const float* __restrict__ att_d,
                                                   float* __restrict__ a_src,
                                                   float* __restrict__ a_dst, int N) {
    int wv = threadIdx.x >> 6, lane = threadIdx.x & 63;
    int n = blockIdx.x * 4 + wv;
    if (n >= N) return;
    u16x4 g4 = *(const u16x4*)(Gb + (size_t)n * 256 + lane * 4);
    f32x4 g;
    g.x = bf2f(g4.x); g.y = bf2f(g4.y); g.z = bf2f(g4.z); g.w = bf2f(g4.w);
    f32x4 s4 = ((const f32x4*)att_s)[lane];
    f32x4 d4 = ((const f32x4*)att_d)[lane];
    f32x4 p = g * s4, q = g * d4;
    float ps = p.x + p.y + p.z + p.w;
    float pd = q.x + q.y + q.z + q.w;
#pragma unroll
    for (int off = 1; off < 16; off <<= 1) {
        ps += __shfl_xor(ps, off);
        pd += __shfl_xor(pd, off);
    }
    if ((lane & 15) == 0) {
        int head = lane >> 4;
        a_src[n * 4 + head] = ps;
        a_dst[n * 4 + head] = pd;
    }
}

// ---------------- fused softmax-weight + gather (ONE wave = ONE block = ONE node) ----
// 1 node/block removes intra-block load imbalance (max-of-4 Poisson straggler);
// scheduler backfills finished nodes immediately.
// Staging computes ev = exp(leaky(a_src[s]+a_dst[n])) (no max subtraction;
// softmax shift-invariant, alphas O(10)); inner loop keeps 4 rows in flight
// per half-wave (indices/weights broadcast from LDS -- no dependent chain).
// outF != null -> fp32 (+bias), no relu (final layer)
// outB != null -> relu(h)+bias as bf16 RNE (next layer's GEMM input)
__global__ __launch_bounds__(64) void gather_kernel(const unsigned short* __restrict__ Gb,
                                                    const float* __restrict__ a_src,
                                                    const float* __restrict__ a_dst,
                                                    const int* __restrict__ row_ptr,
                                                    const int* __restrict__ srcs,
                                                    const float* __restrict__ bias,
                                                    float* __restrict__ outF,
                                                    unsigned short* __restrict__ outB,
                                                    int N) {
    __shared__ int s_lds[64];
    __shared__ f32x4 w_lds[64];
    int lane = threadIdx.x;
    int n = blockIdx.x;
    if (n >= N) return;
    int half = lane >> 5;   // which edge of a pair
    int sl = lane & 31;     // 16B slice of the 512B row
    int head = sl >> 3;

    int start = row_ptr[n], end = row_ptr[n + 1];
    const f32x4* as4p = (const f32x4*)a_src;
    f32x4 adn4 = *(const f32x4*)(a_dst + (size_t)n * 4);

    float acc[8] = {0.f, 0.f, 0.f, 0.f, 0.f, 0.f, 0.f, 0.f};
    f32x4 dsum4 = {0.f, 0.f, 0.f, 0.f};

    for (int c0 = start; c0 < end; c0 += 64) {
        int cnt = min(64, end - c0);
        if (lane < cnt) {
            int s = srcs[c0 + lane];
            f32x4 ev = exp4(lky4(as4p[s] + adn4));
            s_lds[lane] = s;
            w_lds[lane] = ev;
            dsum4 += ev;
        }
        // wave-private staging; compiler inserts lgkmcnt waits before reads

        int j = 0;
        // 4 rows in flight per half-wave
        for (; j + 7 < cnt; j += 8) {
            int sv_[4]; float wv_[4];
#pragma unroll
            for (int t = 0; t < 4; t++) {
                int e = j + 2 * t + half;
                sv_[t] = s_lds[e];
                wv_[t] = ((const float*)&w_lds[e])[head];
            }
            u16x8 gv_[4];
#pragma unroll
            for (int t = 0; t < 4; t++)
                gv_[t] = *(const u16x8*)(Gb + (size_t)sv_[t] * 256 + sl * 8);
#pragma unroll
            for (int t = 0; t < 4; t++)
#pragma unroll
                for (int k = 0; k < 8; k++)
                    acc[k] = fmaf(bf2f(gv_[t][k]), wv_[t], acc[k]);
        }
        for (; j < cnt; j += 2) {
            int e = j + half;
            if (e < cnt) {
                int s0 = s_lds[e];
                float w0 = ((const float*)&w_lds[e])[head];
                u16x8 g0 = *(const u16x8*)(Gb + (size_t)s0 * 256 + sl * 8);
#pragma unroll
                for (int k = 0; k < 8; k++)
                    acc[k] = fmaf(bf2f(g0[k]), w0, acc[k]);
            }
        }
    }

    // combine halves + denominator reduce
#pragma unroll
    for (int k = 0; k < 8; k++) acc[k] += __shfl_xor(acc[k], 32);
#pragma unroll
    for (int off = 32; off; off >>= 1) {
        dsum4.x += __shfl_xor(dsum4.x, off);
        dsum4.y += __shfl_xor(dsum4.y, off);
        dsum4.z += __shfl_xor(dsum4.z, off);
        dsum4.w += __shfl_xor(dsum4.w, off);
    }
    float den = head == 0 ? dsum4.x : head == 1 ? dsum4.y : head == 2 ? dsum4.z : dsum4.w;
    float rden = 1.0f / den;

    float r[8];
    const float* bp = bias + sl * 8;
#pragma unroll
    for (int k = 0; k < 8; k++) r[k] = acc[k] * rden + bp[k];

    if (outF) {
        if (half == 0) {
            f32x4 v0 = {r[0], r[1], r[2], r[3]};
            f32x4 v1 = {r[4], r[5], r[6], r[7]};
            f32x4* op = (f32x4*)(outF + (size_t)n * 256 + sl * 8);
            op[0] = v0; op[1] = v1;
        }
    } else {
        if (half == 0) {
            u16x8 v;
#pragma unroll
            for (int k = 0; k < 8; k++) v[k] = f2bf_rne(fmaxf(r[k], 0.f));
            *(u16x8*)(outB + (size_t)n * 256 + sl * 8) = v;
        }
    }
}

// ---------------- launch ----------------

extern "C" void kernel_launch(void* const* d_in, const int* in_sizes, int n_in,
                              void* d_out, int out_size, void* d_ws, size_t ws_size,
                              hipStream_t stream) {
    const float* x   = (const float*)d_in[0];
    const int*   ei  = (const int*)d_in[1];
    const float* W1  = (const float*)d_in[2];
    const float* as1 = (const float*)d_in[3];
    const float* ad1 = (const float*)d_in[4];
    const float* b1  = (const float*)d_in[5];
    const float* W2  = (const float*)d_in[6];
    const float* as2 = (const float*)d_in[7];
    const float* ad2 = (const float*)d_in[8];
    const float* b2  = (const float*)d_in[9];

    int N = in_sizes[0] / 256;
    int E = in_sizes[1] / 2;
    int Etot = E + N;
    const int* srcE = ei;
    const int* dstE = ei + E;
    float* out = (float*)d_out;

    char* w = (char*)d_ws;
    size_t used = 0;
    auto alloc = [&](size_t bytes) -> char* {
        char* p = w + used;
        used += (bytes + 255) & ~(size_t)255;
        return p;
    };
    unsigned short* Gb = (unsigned short*)alloc((size_t)N * 256 * 2);  // GEMM output (bf16)
    unsigned short* Ab = (unsigned short*)alloc((size_t)N * 256 * 2);  // GEMM input (bf16)
    float* a_src   = (float*)alloc((size_t)N * 4 * 4);
    float* a_dst   = (float*)alloc((size_t)N * 4 * 4);
    int* counts    = (int*)alloc((size_t)N * 4);     // doubles as `fill` for scatter
    int* partial   = (int*)alloc((size_t)N * 4);
    int* row_ptr   = (int*)alloc(((size_t)N + 1) * 4);
    int* srcs      = (int*)alloc((size_t)Etot * 4);
    int* blockSums = (int*)alloc(256 * 4);
    unsigned short* Bt = (unsigned short*)alloc((size_t)256 * 256 * 2);

    hipMemsetAsync(counts, 0, (size_t)N * 4, stream);

    hist_kernel<<<(Etot + 255) / 256, 256, 0, stream>>>(dstE, counts, E, N);
    int nScanBlocks = (N + 1023) / 1024;
    scan1_kernel<<<nScanBlocks, 256, 0, stream>>>(counts, partial, blockSums, N);
    scan2_kernel<<<1, 64, 0, stream>>>(blockSums, nScanBlocks);
    finalize_kernel<<<(N + 255) / 256, 256, 0, stream>>>(partial, blockSums, row_ptr, N, Etot);
    hipMemsetAsync(counts, 0, (size_t)N * 4, stream);   // reuse as fill
    scatter_kernel<<<(Etot + 255) / 256, 256, 0, stream>>>(srcE, dstE, row_ptr, counts, srcs, E, N);

    int nodeBlocks = (N + 3) / 4;
    dim3 gg((N + 127) / 128, 2);

    // layer 1
    convertA_kernel<<<(N * 64 + 255) / 256, 256, 0, stream>>>(x, Ab, N);
    transposeW_kernel<<<256, 256, 0, stream>>>(W1, Bt);
    gemm_kernel<<<gg, 256, 0, stream>>>(Ab, Bt, Gb, N);
    attn_kernel<<<nodeBlocks, 256, 0, stream>>>(Gb, as1, ad1, a_src, a_dst, N);
    gather_kernel<<<N, 64, 0, stream>>>(Gb, a_src, a_dst, row_ptr, srcs,
                                        b1, nullptr, Ab, N);   // relu+bf16 -> layer-2 A

    // layer 2
    transposeW_kernel<<<256, 256, 0, stream>>>(W2, Bt);
    gemm_kernel<<<gg, 256, 0, stream>>>(Ab, Bt, Gb, N);
    attn_kernel<<<nodeBlocks, 256, 0, stream>>>(Gb, as2, ad2, a_src, a_dst, N);
    gather_kernel<<<N, 64, 0, stream>>>(Gb, a_src, a_dst, row_ptr, srcs,
                                        b2, out, nullptr, N);  // fp32 final
}

// Round 12
// 298.083 us; speedup vs baseline: 2.0009x; 1.0129x over previous
//
#include <hip/hip_runtime.h>
#include <math.h>

#define NEG_SLOPE 0.2f

typedef __attribute__((ext_vector_type(8))) short bf16x8;
typedef __attribute__((ext_vector_type(4))) float f32x4;
typedef __attribute__((ext_vector_type(4))) unsigned short u16x4;
typedef __attribute__((ext_vector_type(8))) unsigned short u16x8;

static __device__ __forceinline__ f32x4 lky4(f32x4 v) {
    f32x4 r;
    r.x = v.x >= 0.f ? v.x : NEG_SLOPE * v.x;
    r.y = v.y >= 0.f ? v.y : NEG_SLOPE * v.y;
    r.z = v.z >= 0.f ? v.z : NEG_SLOPE * v.z;
    r.w = v.w >= 0.f ? v.w : NEG_SLOPE * v.w;
    return r;
}
static __device__ __forceinline__ f32x4 exp4(f32x4 v) {
    f32x4 r;
    r.x = __expf(v.x); r.y = __expf(v.y); r.z = __expf(v.z); r.w = __expf(v.w);
    return r;
}
static __device__ __forceinline__ float bf2f(unsigned short u) {
    return __uint_as_float(((unsigned int)u) << 16);
}
static __device__ __forceinline__ unsigned short f2bf_rne(float f) {
    unsigned int u = __float_as_uint(f);
    u += 0x7fffu + ((u >> 16) & 1u);
    return (unsigned short)(u >> 16);
}

// ---------------- CSR build ----------------

__global__ void hist_kernel(const int* __restrict__ dst, int* __restrict__ counts, int E, int Nn) {
    int i = blockIdx.x * blockDim.x + threadIdx.x;
    int tot = E + Nn;
    if (i < tot) {
        int d = (i < E) ? dst[i] : (i - E);
        atomicAdd(&counts[d], 1);
    }
}

__global__ void scan1_kernel(const int* __restrict__ counts, int* __restrict__ partial,
                             int* __restrict__ blockSums, int Nn) {
    __shared__ int sh[1024];
    int b = blockIdx.x, t = threadIdx.x;
    int base = b * 1024;
    int orig[4];
    for (int r = 0; r < 4; r++) {
        int i = t + r * 256;
        int v = (base + i < Nn) ? counts[base + i] : 0;
        orig[r] = v;
        sh[i] = v;
    }
    __syncthreads();
    for (int off = 1; off < 1024; off <<= 1) {
        int vals[4];
        for (int r = 0; r < 4; r++) { int i = t + r * 256; vals[r] = (i >= off) ? sh[i - off] : 0; }
        __syncthreads();
        for (int r = 0; r < 4; r++) { int i = t + r * 256; sh[i] += vals[r]; }
        __syncthreads();
    }
    for (int r = 0; r < 4; r++) {
        int i = t + r * 256;
        if (base + i < Nn) partial[base + i] = sh[i] - orig[r];
    }
    if (t == 0) blockSums[b] = sh[1023];
}

// wave-parallel exclusive scan of <=64 block sums
__global__ void scan2_kernel(int* __restrict__ blockSums, int nb) {
    int lane = threadIdx.x;
    int v = (lane < nb) ? blockSums[lane] : 0;
    int orig = v;
#pragma unroll
    for (int off = 1; off < 64; off <<= 1) {
        int u = __shfl_up(v, off);
        if (lane >= off) v += u;
    }
    if (lane < nb) blockSums[lane] = v - orig;   // exclusive
}

// also zeroes counts[] so it can be reused as the scatter fill[] (saves a memset)
__global__ void finalize_kernel(const int* __restrict__ partial, const int* __restrict__ blockOff,
                                int* __restrict__ row_ptr, int* __restrict__ counts,
                                int Nn, int Etot) {
    int i = blockIdx.x * blockDim.x + threadIdx.x;
    if (i < Nn) {
        row_ptr[i] = partial[i] + blockOff[i >> 10];
        counts[i] = 0;
    }
    if (i == 0) row_ptr[Nn] = Etot;
}

__global__ void scatter_kernel(const int* __restrict__ srcE, const int* __restrict__ dstE,
                               const int* __restrict__ row_ptr, int* __restrict__ fill,
                               int* __restrict__ srcs, int E, int Nn) {
    int i = blockIdx.x * blockDim.x + threadIdx.x;
    int tot = E + Nn;
    if (i < tot) {
        int s, d;
        if (i < E) { s = srcE[i]; d = dstE[i]; }
        else       { s = d = i - E; }
        int pos = row_ptr[d] + atomicAdd(&fill[d], 1);
        srcs[pos] = s;
    }
}

// ---------------- fp32 -> bf16 RNE ----------------
__global__ void convertA_kernel(const float* __restrict__ X, unsigned short* __restrict__ Ab,
                                int rows) {
    int t = blockIdx.x * 256 + threadIdx.x;
    if (t >= rows * 64) return;
    int r = t >> 6, c4 = t & 63;
    f32x4 v = *((const f32x4*)(X + ((size_t)r << 8)) + c4);
    u16x4 o;
    o.x = f2bf_rne(v.x); o.y = f2bf_rne(v.y);
    o.z = f2bf_rne(v.z); o.w = f2bf_rne(v.w);
    *(u16x4*)(Ab + (size_t)r * 256 + c4 * 4) = o;
}

// W[k][n] fp32 -> Bt[n][k] bf16 RNE  (Bt: [256][256])
__global__ void transposeW_kernel(const float* __restrict__ W, unsigned short* __restrict__ Bt) {
    int t = blockIdx.x * 256 + threadIdx.x;   // 65536 threads
    int n = t >> 8, k = t & 255;
    Bt[(size_t)n * 256 + k] = f2bf_rne(W[k * 256 + n]);
}

// ---------------- bf16 MFMA GEMM, K=256, 2-phase double-buffered ----------------
// Gb[rows,256] (bf16 RNE) = Ab x Bt^T.
// 1-D grid nwg = Mblocks*2 with bijective XCD-chunk swizzle (m204): both
// column-blocks of an A-row-panel land on the same XCD -> second A-panel read
// is an L2 hit.
__global__ __launch_bounds__(256) void gemm_kernel(const unsigned short* __restrict__ Ab,
                                                   const unsigned short* __restrict__ Bt,
                                                   unsigned short* __restrict__ Gb,
                                                   int rows, int nwg) {
    // bijective XCD swizzle: dispatch idx -> logical block
    int orig = blockIdx.x;
    int q = nwg >> 3, r8 = nwg & 7;
    int xcd = orig & 7, idx = orig >> 3;
    int logical = (xcd < r8 ? xcd * (q + 1) : r8 * (q + 1) + (xcd - r8) * q) + idx;
    int bm = (logical >> 1) * 128;
    int bn = (logical & 1) * 128;

    __shared__ __align__(128) unsigned char smem[65536];   // 2 x (As 16KB + Bs 16KB)

    int tid = threadIdx.x;
    int lane = tid & 63, wid = tid >> 6;
    int wr = wid >> 1, wc = wid & 1;

    f32x4 zero4 = {0.f, 0.f, 0.f, 0.f};
    f32x4 acc[4][4];
#pragma unroll
    for (int i = 0; i < 4; i++)
#pragma unroll
        for (int j = 0; j < 4; j++) acc[i][j] = zero4;

    int sr = tid >> 3;   // 0..31
    int sc = tid & 7;    // chunk 0..7

    auto stage = [&](int kt, int buf) {
        unsigned short* As = (unsigned short*)(smem + buf * 32768);
        unsigned short* Bs = As + 8192;
#pragma unroll
        for (int q2 = 0; q2 < 4; q2++) {
            int rt = q2 * 32 + sr;
            int gr = bm + rt; if (gr >= rows) gr = rows - 1;
            int cg = sc ^ (rt & 7);
            const unsigned short* gp = Ab + (size_t)gr * 256 + kt + cg * 8;
            unsigned short* lp = As + rt * 64 + sc * 8;
            __builtin_amdgcn_global_load_lds(
                (__attribute__((address_space(1))) void*)(uintptr_t)gp,
                (__attribute__((address_space(3))) void*)lp, 16, 0, 0);
        }
#pragma unroll
        for (int q2 = 0; q2 < 4; q2++) {
            int rt = q2 * 32 + sr;
            int gn = bn + rt;
            int cg = sc ^ (rt & 7);
            const unsigned short* gp = Bt + (size_t)gn * 256 + kt + cg * 8;
            unsigned short* lp = Bs + rt * 64 + sc * 8;
            __builtin_amdgcn_global_load_lds(
                (__attribute__((address_space(1))) void*)(uintptr_t)gp,
                (__attribute__((address_space(3))) void*)lp, 16, 0, 0);
        }
    };

    stage(0, 0);
    __syncthreads();

    for (int kt = 0; kt < 4; kt++) {
        if (kt < 3) stage((kt + 1) * 64, (kt + 1) & 1);
        unsigned short* As = (unsigned short*)(smem + (kt & 1) * 32768);
        unsigned short* Bs = As + 8192;
#pragma unroll
        for (int ks = 0; ks < 2; ks++) {
            bf16x8 af[4], bfr[4];
#pragma unroll
            for (int f = 0; f < 4; f++) {
                int r = wr * 64 + f * 16 + (lane & 15);
                int c = (ks * 4 + (lane >> 4)) ^ (r & 7);
                af[f] = *(const bf16x8*)(As + r * 64 + c * 8);
                int rb = wc * 64 + f * 16 + (lane & 15);
                int cb = (ks * 4 + (lane >> 4)) ^ (rb & 7);
                bfr[f] = *(const bf16x8*)(Bs + rb * 64 + cb * 8);
            }
#pragma unroll
            for (int i = 0; i < 4; i++)
#pragma unroll
                for (int j = 0; j < 4; j++)
                    acc[i][j] = __builtin_amdgcn_mfma_f32_16x16x32_bf16(af[i], bfr[j], acc[i][j], 0, 0, 0);
        }
        __syncthreads();
    }

    int r0 = wr * 64 + (lane >> 4) * 4;
    int c0 = wc * 64 + (lane & 15);
#pragma unroll
    for (int i = 0; i < 4; i++) {
#pragma unroll
        for (int j = 0; j < 4; j++) {
#pragma unroll
            for (int rg = 0; rg < 4; rg++) {
                int lr = bm + r0 + i * 16 + rg;
                if (lr < rows) {
                    int col = bn + c0 + j * 16;
                    Gb[(size_t)lr * 256 + col] = f2bf_rne(acc[i][j][rg]);
                }
            }
        }
    }
}

// ---------------- attention coefficients (wave per node, bf16 G) ----------------
__global__ __launch_bounds__(256) void attn_kernel(const unsigned short* __restrict__ Gb,
                                                   const float* __restrict__ att_s,
                                                   const float* __restrict__ att_d,
                                                   float* __restrict__ a_src,
                                                   float* __restrict__ a_dst, int N) {
    int wv = threadIdx.x >> 6, lane = threadIdx.x & 63;
    int n = blockIdx.x * 4 + wv;
    if (n >= N) return;
    u16x4 g4 = *(const u16x4*)(Gb + (size_t)n * 256 + lane * 4);
    f32x4 g;
    g.x = bf2f(g4.x); g.y = bf2f(g4.y); g.z = bf2f(g4.z); g.w = bf2f(g4.w);
    f32x4 s4 = ((const f32x4*)att_s)[lane];
    f32x4 d4 = ((const f32x4*)att_d)[lane];
    f32x4 p = g * s4, q = g * d4;
    float ps = p.x + p.y + p.z + p.w;
    float pd = q.x + q.y + q.z + q.w;
#pragma unroll
    for (int off = 1; off < 16; off <<= 1) {
        ps += __shfl_xor(ps, off);
        pd += __shfl_xor(pd, off);
    }
    if ((lane & 15) == 0) {
        int head = lane >> 4;
        a_src[n * 4 + head] = ps;
        a_dst[n * 4 + head] = pd;
    }
}

// ---------------- fused softmax-weight + gather (ONE wave = ONE block = ONE node) ----
// Staging computes ev = exp(leaky(a_src[s]+a_dst[n])) (no max subtraction;
// softmax shift-invariant, alphas O(10)); inner loop keeps 4 rows in flight
// per half-wave (indices/weights broadcast from LDS -- no dependent chain).
// outF != null -> fp32 (+bias), no relu (final layer)
// outB != null -> relu(h)+bias as bf16 RNE (next layer's GEMM input)
__global__ __launch_bounds__(64) void gather_kernel(const unsigned short* __restrict__ Gb,
                                                    const float* __restrict__ a_src,
                                                    const float* __restrict__ a_dst,
                                                    const int* __restrict__ row_ptr,
                                                    const int* __restrict__ srcs,
                                                    const float* __restrict__ bias,
                                                    float* __restrict__ outF,
                                                    unsigned short* __restrict__ outB,
                                                    int N) {
    __shared__ int s_lds[64];
    __shared__ f32x4 w_lds[64];
    int lane = threadIdx.x;
    int n = blockIdx.x;
    if (n >= N) return;
    int half = lane >> 5;   // which edge of a pair
    int sl = lane & 31;     // 16B slice of the 512B row
    int head = sl >> 3;

    int start = row_ptr[n], end = row_ptr[n + 1];
    const f32x4* as4p = (const f32x4*)a_src;
    f32x4 adn4 = *(const f32x4*)(a_dst + (size_t)n * 4);

    float acc[8] = {0.f, 0.f, 0.f, 0.f, 0.f, 0.f, 0.f, 0.f};
    f32x4 dsum4 = {0.f, 0.f, 0.f, 0.f};

    for (int c0 = start; c0 < end; c0 += 64) {
        int cnt = min(64, end - c0);
        if (lane < cnt) {
            int s = srcs[c0 + lane];
            f32x4 ev = exp4(lky4(as4p[s] + adn4));
            s_lds[lane] = s;
            w_lds[lane] = ev;
            dsum4 += ev;
        }
        // wave-private staging; compiler inserts lgkmcnt waits before reads

        int j = 0;
        // 4 rows in flight per half-wave
        for (; j + 7 < cnt; j += 8) {
            int sv_[4]; float wv_[4];
#pragma unroll
            for (int t = 0; t < 4; t++) {
                int e = j + 2 * t + half;
                sv_[t] = s_lds[e];
                wv_[t] = ((const float*)&w_lds[e])[head];
            }
            u16x8 gv_[4];
#pragma unroll
            for (int t = 0; t < 4; t++)
                gv_[t] = *(const u16x8*)(Gb + (size_t)sv_[t] * 256 + sl * 8);
#pragma unroll
            for (int t = 0; t < 4; t++)
#pragma unroll
                for (int k = 0; k < 8; k++)
                    acc[k] = fmaf(bf2f(gv_[t][k]), wv_[t], acc[k]);
        }
        for (; j < cnt; j += 2) {
            int e = j + half;
            if (e < cnt) {
                int s0 = s_lds[e];
                float w0 = ((const float*)&w_lds[e])[head];
                u16x8 g0 = *(const u16x8*)(Gb + (size_t)s0 * 256 + sl * 8);
#pragma unroll
                for (int k = 0; k < 8; k++)
                    acc[k] = fmaf(bf2f(g0[k]), w0, acc[k]);
            }
        }
    }

    // combine halves + denominator reduce
#pragma unroll
    for (int k = 0; k < 8; k++) acc[k] += __shfl_xor(acc[k], 32);
#pragma unroll
    for (int off = 32; off; off >>= 1) {
        dsum4.x += __shfl_xor(dsum4.x, off);
        dsum4.y += __shfl_xor(dsum4.y, off);
        dsum4.z += __shfl_xor(dsum4.z, off);
        dsum4.w += __shfl_xor(dsum4.w, off);
    }
    float den = head == 0 ? dsum4.x : head == 1 ? dsum4.y : head == 2 ? dsum4.z : dsum4.w;
    float rden = 1.0f / den;

    float r[8];
    const float* bp = bias + sl * 8;
#pragma unroll
    for (int k = 0; k < 8; k++) r[k] = acc[k] * rden + bp[k];

    if (outF) {
        if (half == 0) {
            f32x4 v0 = {r[0], r[1], r[2], r[3]};
            f32x4 v1 = {r[4], r[5], r[6], r[7]};
            f32x4* op = (f32x4*)(outF + (size_t)n * 256 + sl * 8);
            op[0] = v0; op[1] = v1;
        }
    } else {
        if (half == 0) {
            u16x8 v;
#pragma unroll
            for (int k = 0; k < 8; k++) v[k] = f2bf_rne(fmaxf(r[k], 0.f));
            *(u16x8*)(outB + (size_t)n * 256 + sl * 8) = v;
        }
    }
}

// ---------------- launch ----------------

extern "C" void kernel_launch(void* const* d_in, const int* in_sizes, int n_in,
                              void* d_out, int out_size, void* d_ws, size_t ws_size,
                              hipStream_t stream) {
    const float* x   = (const float*)d_in[0];
    const int*   ei  = (const int*)d_in[1];
    const float* W1  = (const float*)d_in[2];
    const float* as1 = (const float*)d_in[3];
    const float* ad1 = (const float*)d_in[4];
    const float* b1  = (const float*)d_in[5];
    const float* W2  = (const float*)d_in[6];
    const float* as2 = (const float*)d_in[7];
    const float* ad2 = (const float*)d_in[8];
    const float* b2  = (const float*)d_in[9];

    int N = in_sizes[0] / 256;
    int E = in_sizes[1] / 2;
    int Etot = E + N;
    const int* srcE = ei;
    const int* dstE = ei + E;
    float* out = (float*)d_out;

    char* w = (char*)d_ws;
    size_t used = 0;
    auto alloc = [&](size_t bytes) -> char* {
        char* p = w + used;
        used += (bytes + 255) & ~(size_t)255;
        return p;
    };
    unsigned short* Gb = (unsigned short*)alloc((size_t)N * 256 * 2);  // GEMM output (bf16)
    unsigned short* Ab = (unsigned short*)alloc((size_t)N * 256 * 2);  // GEMM input (bf16)
    float* a_src   = (float*)alloc((size_t)N * 4 * 4);
    float* a_dst   = (float*)alloc((size_t)N * 4 * 4);
    int* counts    = (int*)alloc((size_t)N * 4);     // doubles as `fill` for scatter
    int* partial   = (int*)alloc((size_t)N * 4);
    int* row_ptr   = (int*)alloc(((size_t)N + 1) * 4);
    int* srcs      = (int*)alloc((size_t)Etot * 4);
    int* blockSums = (int*)alloc(256 * 4);
    unsigned short* Bt = (unsigned short*)alloc((size_t)256 * 256 * 2);

    hipMemsetAsync(counts, 0, (size_t)N * 4, stream);

    hist_kernel<<<(Etot + 255) / 256, 256, 0, stream>>>(dstE, counts, E, N);
    int nScanBlocks = (N + 1023) / 1024;
    scan1_kernel<<<nScanBlocks, 256, 0, stream>>>(counts, partial, blockSums, N);
    scan2_kernel<<<1, 64, 0, stream>>>(blockSums, nScanBlocks);
    finalize_kernel<<<(N + 255) / 256, 256, 0, stream>>>(partial, blockSums, row_ptr, counts, N, Etot);
    scatter_kernel<<<(Etot + 255) / 256, 256, 0, stream>>>(srcE, dstE, row_ptr, counts, srcs, E, N);

    int nodeBlocks = (N + 3) / 4;
    int nwg = ((N + 127) / 128) * 2;

    // layer 1
    convertA_kernel<<<(N * 64 + 255) / 256, 256, 0, stream>>>(x, Ab, N);
    transposeW_kernel<<<256, 256, 0, stream>>>(W1, Bt);
    gemm_kernel<<<nwg, 256, 0, stream>>>(Ab, Bt, Gb, N, nwg);
    attn_kernel<<<nodeBlocks, 256, 0, stream>>>(Gb, as1, ad1, a_src, a_dst, N);
    gather_kernel<<<N, 64, 0, stream>>>(Gb, a_src, a_dst, row_ptr, srcs,
                                        b1, nullptr, Ab, N);   // relu+bf16 -> layer-2 A

    // layer 2
    transposeW_kernel<<<256, 256, 0, stream>>>(W2, Bt);
    gemm_kernel<<<nwg, 256, 0, stream>>>(Ab, Bt, Gb, N, nwg);
    attn_kernel<<<nodeBlocks, 256, 0, stream>>>(Gb, as2, ad2, a_src, a_dst, N);
    gather_kernel<<<N, 64, 0, stream>>>(Gb, a_src, a_dst, row_ptr, srcs,
                                        b2, out, nullptr, N);  // fp32 final
}

// Round 13
// 290.375 us; speedup vs baseline: 2.0540x; 1.0265x over previous
//
#include <hip/hip_runtime.h>
#include <math.h>

#define NEG_SLOPE 0.2f

typedef __attribute__((ext_vector_type(8))) short bf16x8;
typedef __attribute__((ext_vector_type(4))) float f32x4;
typedef __attribute__((ext_vector_type(4))) unsigned short u16x4;
typedef __attribute__((ext_vector_type(8))) unsigned short u16x8;

static __device__ __forceinline__ f32x4 lky4(f32x4 v) {
    f32x4 r;
    r.x = v.x >= 0.f ? v.x : NEG_SLOPE * v.x;
    r.y = v.y >= 0.f ? v.y : NEG_SLOPE * v.y;
    r.z = v.z >= 0.f ? v.z : NEG_SLOPE * v.z;
    r.w = v.w >= 0.f ? v.w : NEG_SLOPE * v.w;
    return r;
}
static __device__ __forceinline__ f32x4 exp4(f32x4 v) {
    f32x4 r;
    r.x = __expf(v.x); r.y = __expf(v.y); r.z = __expf(v.z); r.w = __expf(v.w);
    return r;
}
static __device__ __forceinline__ float bf2f(unsigned short u) {
    return __uint_as_float(((unsigned int)u) << 16);
}
static __device__ __forceinline__ unsigned short f2bf_rne(float f) {
    unsigned int u = __float_as_uint(f);
    u += 0x7fffu + ((u >> 16) & 1u);
    return (unsigned short)(u >> 16);
}

// ---------------- CSR build ----------------

__global__ void hist_kernel(const int* __restrict__ dst, int* __restrict__ counts, int E, int Nn) {
    int i = blockIdx.x * blockDim.x + threadIdx.x;
    int tot = E + Nn;
    if (i < tot) {
        int d = (i < E) ? dst[i] : (i - E);
        atomicAdd(&counts[d], 1);
    }
}

__global__ void scan1_kernel(const int* __restrict__ counts, int* __restrict__ partial,
                             int* __restrict__ blockSums, int Nn) {
    __shared__ int sh[1024];
    int b = blockIdx.x, t = threadIdx.x;
    int base = b * 1024;
    int orig[4];
    for (int r = 0; r < 4; r++) {
        int i = t + r * 256;
        int v = (base + i < Nn) ? counts[base + i] : 0;
        orig[r] = v;
        sh[i] = v;
    }
    __syncthreads();
    for (int off = 1; off < 1024; off <<= 1) {
        int vals[4];
        for (int r = 0; r < 4; r++) { int i = t + r * 256; vals[r] = (i >= off) ? sh[i - off] : 0; }
        __syncthreads();
        for (int r = 0; r < 4; r++) { int i = t + r * 256; sh[i] += vals[r]; }
        __syncthreads();
    }
    for (int r = 0; r < 4; r++) {
        int i = t + r * 256;
        if (base + i < Nn) partial[base + i] = sh[i] - orig[r];
    }
    if (t == 0) blockSums[b] = sh[1023];
}

// finalize with inlined wave-scan of blockSums (<=64 entries, read-only);
// also zeroes counts[] for reuse as the scatter fill[] (saves a memset + a dispatch)
__global__ void finalize_kernel(const int* __restrict__ partial, const int* __restrict__ blockSums,
                                int* __restrict__ row_ptr, int* __restrict__ counts,
                                int Nn, int Etot, int nb) {
    __shared__ int sh[64];
    int t = threadIdx.x;
    if (t < 64) {
        int v = (t < nb) ? blockSums[t] : 0;
        int orig = v;
#pragma unroll
        for (int off = 1; off < 64; off <<= 1) {
            int u = __shfl_up(v, off);
            if (t >= off) v += u;
        }
        sh[t] = v - orig;   // exclusive prefix
    }
    __syncthreads();
    int i = blockIdx.x * blockDim.x + t;
    if (i < Nn) {
        row_ptr[i] = partial[i] + sh[i >> 10];
        counts[i] = 0;
    }
    if (i == 0) row_ptr[Nn] = Etot;
}

__global__ void scatter_kernel(const int* __restrict__ srcE, const int* __restrict__ dstE,
                               const int* __restrict__ row_ptr, int* __restrict__ fill,
                               int* __restrict__ srcs, int E, int Nn) {
    int i = blockIdx.x * blockDim.x + threadIdx.x;
    int tot = E + Nn;
    if (i < tot) {
        int s, d;
        if (i < E) { s = srcE[i]; d = dstE[i]; }
        else       { s = d = i - E; }
        int pos = row_ptr[d] + atomicAdd(&fill[d], 1);
        srcs[pos] = s;
    }
}

// ---------------- fused prep: x -> Ab (bf16 RNE) + W1 -> Bt1 + W2 -> Bt2 ----------------
__global__ void prep_kernel(const float* __restrict__ X, unsigned short* __restrict__ Ab,
                            const float* __restrict__ W1, unsigned short* __restrict__ Bt1,
                            const float* __restrict__ W2, unsigned short* __restrict__ Bt2,
                            int rows, int nConv) {
    int b = blockIdx.x;
    if (b < nConv) {
        int t = b * 256 + threadIdx.x;
        if (t >= rows * 64) return;
        int r = t >> 6, c4 = t & 63;
        f32x4 v = *((const f32x4*)(X + ((size_t)r << 8)) + c4);
        u16x4 o;
        o.x = f2bf_rne(v.x); o.y = f2bf_rne(v.y);
        o.z = f2bf_rne(v.z); o.w = f2bf_rne(v.w);
        *(u16x4*)(Ab + (size_t)r * 256 + c4 * 4) = o;
    } else {
        int b2 = b - nConv;
        const float* W = (b2 < 256) ? W1 : W2;
        unsigned short* Bt = (b2 < 256) ? Bt1 : Bt2;
        int bb = (b2 < 256) ? b2 : b2 - 256;
        int t = bb * 256 + threadIdx.x;
        int n = t >> 8, k = t & 255;
        Bt[(size_t)n * 256 + k] = f2bf_rne(W[k * 256 + n]);
    }
}

// ---------------- bf16 MFMA GEMM, K=256, 2-phase double-buffered ----------------
// Gb[rows,256] (bf16 RNE) = Ab x Bt^T.
// 1-D grid nwg with bijective XCD-chunk swizzle (m204): both column-blocks of an
// A-row-panel land on the same XCD -> second A-panel read is an L2 hit.
__global__ __launch_bounds__(256) void gemm_kernel(const unsigned short* __restrict__ Ab,
                                                   const unsigned short* __restrict__ Bt,
                                                   unsigned short* __restrict__ Gb,
                                                   int rows, int nwg) {
    int orig = blockIdx.x;
    int q = nwg >> 3, r8 = nwg & 7;
    int xcd = orig & 7, idx = orig >> 3;
    int logical = (xcd < r8 ? xcd * (q + 1) : r8 * (q + 1) + (xcd - r8) * q) + idx;
    int bm = (logical >> 1) * 128;
    int bn = (logical & 1) * 128;

    __shared__ __align__(128) unsigned char smem[65536];   // 2 x (As 16KB + Bs 16KB)

    int tid = threadIdx.x;
    int lane = tid & 63, wid = tid >> 6;
    int wr = wid >> 1, wc = wid & 1;

    f32x4 zero4 = {0.f, 0.f, 0.f, 0.f};
    f32x4 acc[4][4];
#pragma unroll
    for (int i = 0; i < 4; i++)
#pragma unroll
        for (int j = 0; j < 4; j++) acc[i][j] = zero4;

    int sr = tid >> 3;   // 0..31
    int sc = tid & 7;    // chunk 0..7

    auto stage = [&](int kt, int buf) {
        unsigned short* As = (unsigned short*)(smem + buf * 32768);
        unsigned short* Bs = As + 8192;
#pragma unroll
        for (int q2 = 0; q2 < 4; q2++) {
            int rt = q2 * 32 + sr;
            int gr = bm + rt; if (gr >= rows) gr = rows - 1;
            int cg = sc ^ (rt & 7);
            const unsigned short* gp = Ab + (size_t)gr * 256 + kt + cg * 8;
            unsigned short* lp = As + rt * 64 + sc * 8;
            __builtin_amdgcn_global_load_lds(
                (__attribute__((address_space(1))) void*)(uintptr_t)gp,
                (__attribute__((address_space(3))) void*)lp, 16, 0, 0);
        }
#pragma unroll
        for (int q2 = 0; q2 < 4; q2++) {
            int rt = q2 * 32 + sr;
            int gn = bn + rt;
            int cg = sc ^ (rt & 7);
            const unsigned short* gp = Bt + (size_t)gn * 256 + kt + cg * 8;
            unsigned short* lp = Bs + rt * 64 + sc * 8;
            __builtin_amdgcn_global_load_lds(
                (__attribute__((address_space(1))) void*)(uintptr_t)gp,
                (__attribute__((address_space(3))) void*)lp, 16, 0, 0);
        }
    };

    stage(0, 0);
    __syncthreads();

    for (int kt = 0; kt < 4; kt++) {
        if (kt < 3) stage((kt + 1) * 64, (kt + 1) & 1);
        unsigned short* As = (unsigned short*)(smem + (kt & 1) * 32768);
        unsigned short* Bs = As + 8192;
#pragma unroll
        for (int ks = 0; ks < 2; ks++) {
            bf16x8 af[4], bfr[4];
#pragma unroll
            for (int f = 0; f < 4; f++) {
                int r = wr * 64 + f * 16 + (lane & 15);
                int c = (ks * 4 + (lane >> 4)) ^ (r & 7);
                af[f] = *(const bf16x8*)(As + r * 64 + c * 8);
                int rb = wc * 64 + f * 16 + (lane & 15);
                int cb = (ks * 4 + (lane >> 4)) ^ (rb & 7);
                bfr[f] = *(const bf16x8*)(Bs + rb * 64 + cb * 8);
            }
#pragma unroll
            for (int i = 0; i < 4; i++)
#pragma unroll
                for (int j = 0; j < 4; j++)
                    acc[i][j] = __builtin_amdgcn_mfma_f32_16x16x32_bf16(af[i], bfr[j], acc[i][j], 0, 0, 0);
        }
        __syncthreads();
    }

    int r0 = wr * 64 + (lane >> 4) * 4;
    int c0 = wc * 64 + (lane & 15);
#pragma unroll
    for (int i = 0; i < 4; i++) {
#pragma unroll
        for (int j = 0; j < 4; j++) {
#pragma unroll
            for (int rg = 0; rg < 4; rg++) {
                int lr = bm + r0 + i * 16 + rg;
                if (lr < rows) {
                    int col = bn + c0 + j * 16;
                    Gb[(size_t)lr * 256 + col] = f2bf_rne(acc[i][j][rg]);
                }
            }
        }
    }
}

// ---------------- attention coefficients (wave per node, bf16 G) ----------------
__global__ __launch_bounds__(256) void attn_kernel(const unsigned short* __restrict__ Gb,
                                                   const float* __restrict__ att_s,
                                                   const float* __restrict__ att_d,
                                                   float* __restrict__ a_src,
                                                   float* __restrict__ a_dst, int N) {
    int wv = threadIdx.x >> 6, lane = threadIdx.x & 63;
    int n = blockIdx.x * 4 + wv;
    if (n >= N) return;
    u16x4 g4 = *(const u16x4*)(Gb + (size_t)n * 256 + lane * 4);
    f32x4 g;
    g.x = bf2f(g4.x); g.y = bf2f(g4.y); g.z = bf2f(g4.z); g.w = bf2f(g4.w);
    f32x4 s4 = ((const f32x4*)att_s)[lane];
    f32x4 d4 = ((const f32x4*)att_d)[lane];
    f32x4 p = g * s4, q = g * d4;
    float ps = p.x + p.y + p.z + p.w;
    float pd = q.x + q.y + q.z + q.w;
#pragma unroll
    for (int off = 1; off < 16; off <<= 1) {
        ps += __shfl_xor(ps, off);
        pd += __shfl_xor(pd, off);
    }
    if ((lane & 15) == 0) {
        int head = lane >> 4;
        a_src[n * 4 + head] = ps;
        a_dst[n * 4 + head] = pd;
    }
}

// ---------------- fused softmax-weight + gather (ONE wave = ONE block = ONE node) ----
// Staging computes ev = exp(leaky(a_src[s]+a_dst[n])) (no max subtraction;
// softmax shift-invariant, alphas O(10)); inner loop keeps 4 rows in flight
// per half-wave (indices/weights broadcast from LDS -- no dependent chain).
// outF != null -> fp32 (+bias), no relu (final layer)
// outB != null -> relu(h)+bias as bf16 RNE (next layer's GEMM input)
__global__ __launch_bounds__(64) void gather_kernel(const unsigned short* __restrict__ Gb,
                                                    const float* __restrict__ a_src,
                                                    const float* __restrict__ a_dst,
                                                    const int* __restrict__ row_ptr,
                                                    const int* __restrict__ srcs,
                                                    const float* __restrict__ bias,
                                                    float* __restrict__ outF,
                                                    unsigned short* __restrict__ outB,
                                                    int N) {
    __shared__ int s_lds[64];
    __shared__ f32x4 w_lds[64];
    int lane = threadIdx.x;
    int n = blockIdx.x;
    if (n >= N) return;
    int half = lane >> 5;   // which edge of a pair
    int sl = lane & 31;     // 16B slice of the 512B row
    int head = sl >> 3;

    int start = row_ptr[n], end = row_ptr[n + 1];
    const f32x4* as4p = (const f32x4*)a_src;
    f32x4 adn4 = *(const f32x4*)(a_dst + (size_t)n * 4);

    float acc[8] = {0.f, 0.f, 0.f, 0.f, 0.f, 0.f, 0.f, 0.f};
    f32x4 dsum4 = {0.f, 0.f, 0.f, 0.f};

    for (int c0 = start; c0 < end; c0 += 64) {
        int cnt = min(64, end - c0);
        if (lane < cnt) {
            int s = srcs[c0 + lane];
            f32x4 ev = exp4(lky4(as4p[s] + adn4));
            s_lds[lane] = s;
            w_lds[lane] = ev;
            dsum4 += ev;
        }
        // wave-private staging; compiler inserts lgkmcnt waits before reads

        int j = 0;
        // 4 rows in flight per half-wave
        for (; j + 7 < cnt; j += 8) {
            int sv_[4]; float wv_[4];
#pragma unroll
            for (int t = 0; t < 4; t++) {
                int e = j + 2 * t + half;
                sv_[t] = s_lds[e];
                wv_[t] = ((const float*)&w_lds[e])[head];
            }
            u16x8 gv_[4];
#pragma unroll
            for (int t = 0; t < 4; t++)
                gv_[t] = *(const u16x8*)(Gb + (size_t)sv_[t] * 256 + sl * 8);
#pragma unroll
            for (int t = 0; t < 4; t++)
#pragma unroll
                for (int k = 0; k < 8; k++)
                    acc[k] = fmaf(bf2f(gv_[t][k]), wv_[t], acc[k]);
        }
        for (; j < cnt; j += 2) {
            int e = j + half;
            if (e < cnt) {
                int s0 = s_lds[e];
                float w0 = ((const float*)&w_lds[e])[head];
                u16x8 g0 = *(const u16x8*)(Gb + (size_t)s0 * 256 + sl * 8);
#pragma unroll
                for (int k = 0; k < 8; k++)
                    acc[k] = fmaf(bf2f(g0[k]), w0, acc[k]);
            }
        }
    }

    // combine halves + denominator reduce
#pragma unroll
    for (int k = 0; k < 8; k++) acc[k] += __shfl_xor(acc[k], 32);
#pragma unroll
    for (int off = 32; off; off >>= 1) {
        dsum4.x += __shfl_xor(dsum4.x, off);
        dsum4.y += __shfl_xor(dsum4.y, off);
        dsum4.z += __shfl_xor(dsum4.z, off);
        dsum4.w += __shfl_xor(dsum4.w, off);
    }
    float den = head == 0 ? dsum4.x : head == 1 ? dsum4.y : head == 2 ? dsum4.z : dsum4.w;
    float rden = 1.0f / den;

    float r[8];
    const float* bp = bias + sl * 8;
#pragma unroll
    for (int k = 0; k < 8; k++) r[k] = acc[k] * rden + bp[k];

    if (outF) {
        if (half == 0) {
            f32x4 v0 = {r[0], r[1], r[2], r[3]};
            f32x4 v1 = {r[4], r[5], r[6], r[7]};
            f32x4* op = (f32x4*)(outF + (size_t)n * 256 + sl * 8);
            op[0] = v0; op[1] = v1;
        }
    } else {
        if (half == 0) {
            u16x8 v;
#pragma unroll
            for (int k = 0; k < 8; k++) v[k] = f2bf_rne(fmaxf(r[k], 0.f));
            *(u16x8*)(outB + (size_t)n * 256 + sl * 8) = v;
        }
    }
}

// ---------------- launch ----------------

extern "C" void kernel_launch(void* const* d_in, const int* in_sizes, int n_in,
                              void* d_out, int out_size, void* d_ws, size_t ws_size,
                              hipStream_t stream) {
    const float* x   = (const float*)d_in[0];
    const int*   ei  = (const int*)d_in[1];
    const float* W1  = (const float*)d_in[2];
    const float* as1 = (const float*)d_in[3];
    const float* ad1 = (const float*)d_in[4];
    const float* b1  = (const float*)d_in[5];
    const float* W2  = (const float*)d_in[6];
    const float* as2 = (const float*)d_in[7];
    const float* ad2 = (const float*)d_in[8];
    const float* b2  = (const float*)d_in[9];

    int N = in_sizes[0] / 256;
    int E = in_sizes[1] / 2;
    int Etot = E + N;
    const int* srcE = ei;
    const int* dstE = ei + E;
    float* out = (float*)d_out;

    char* w = (char*)d_ws;
    size_t used = 0;
    auto alloc = [&](size_t bytes) -> char* {
        char* p = w + used;
        used += (bytes + 255) & ~(size_t)255;
        return p;
    };
    unsigned short* Gb = (unsigned short*)alloc((size_t)N * 256 * 2);  // GEMM output (bf16)
    unsigned short* Ab = (unsigned short*)alloc((size_t)N * 256 * 2);  // GEMM input (bf16)
    float* a_src   = (float*)alloc((size_t)N * 4 * 4);
    float* a_dst   = (float*)alloc((size_t)N * 4 * 4);
    int* counts    = (int*)alloc((size_t)N * 4);     // doubles as `fill` for scatter
    int* partial   = (int*)alloc((size_t)N * 4);
    int* row_ptr   = (int*)alloc(((size_t)N + 1) * 4);
    int* srcs      = (int*)alloc((size_t)Etot * 4);
    int* blockSums = (int*)alloc(256 * 4);
    unsigned short* Bt1 = (unsigned short*)alloc((size_t)256 * 256 * 2);
    unsigned short* Bt2 = (unsigned short*)alloc((size_t)256 * 256 * 2);

    hipMemsetAsync(counts, 0, (size_t)N * 4, stream);

    // fused prep: x->Ab, W1->Bt1, W2->Bt2
    int nConv = (N * 64 + 255) / 256;
    prep_kernel<<<nConv + 512, 256, 0, stream>>>(x, Ab, W1, Bt1, W2, Bt2, N, nConv);

    hist_kernel<<<(Etot + 255) / 256, 256, 0, stream>>>(dstE, counts, E, N);
    int nScanBlocks = (N + 1023) / 1024;
    scan1_kernel<<<nScanBlocks, 256, 0, stream>>>(counts, partial, blockSums, N);
    finalize_kernel<<<(N + 255) / 256, 256, 0, stream>>>(partial, blockSums, row_ptr, counts,
                                                         N, Etot, nScanBlocks);
    scatter_kernel<<<(Etot + 255) / 256, 256, 0, stream>>>(srcE, dstE, row_ptr, counts, srcs, E, N);

    int nodeBlocks = (N + 3) / 4;
    int nwg = ((N + 127) / 128) * 2;

    // layer 1
    gemm_kernel<<<nwg, 256, 0, stream>>>(Ab, Bt1, Gb, N, nwg);
    attn_kernel<<<nodeBlocks, 256, 0, stream>>>(Gb, as1, ad1, a_src, a_dst, N);
    gather_kernel<<<N, 64, 0, stream>>>(Gb, a_src, a_dst, row_ptr, srcs,
                                        b1, nullptr, Ab, N);   // relu+bf16 -> layer-2 A

    // layer 2
    gemm_kernel<<<nwg, 256, 0, stream>>>(Ab, Bt2, Gb, N, nwg);
    attn_kernel<<<nodeBlocks, 256, 0, stream>>>(Gb, as2, ad2, a_src, a_dst, N);
    gather_kernel<<<N, 64, 0, stream>>>(Gb, a_src, a_dst, row_ptr, srcs,
                                        b2, out, nullptr, N);  // fp32 final
}